// Round 6
// baseline (692.607 us; speedup 1.0000x reference)
//
#include <hip/hip_runtime.h>
#include <hip/hip_bf16.h>
#include <stdint.h>

// Problem dims (fixed)
#define BB 32
#define TT 2048
#define DD 1024
#define DIMQ 1024
#define MTOT (BB*TT)   // 65536 rows of X flattened

typedef __attribute__((ext_vector_type(8))) __bf16 bf16x8;
typedef __attribute__((ext_vector_type(4))) float f32x4;

__device__ __forceinline__ unsigned short f2bf(float f) {
    unsigned int u = __float_as_uint(f);
    u += 0x7FFF + ((u >> 16) & 1);   // round-to-nearest-even
    return (unsigned short)(u >> 16);
}
__device__ __forceinline__ float bf2f(unsigned short s) {
    return __uint_as_float(((unsigned int)s) << 16);
}

__device__ __forceinline__ void load_lds16(const void* g, void* l) {
    __builtin_amdgcn_global_load_lds(
        (const __attribute__((address_space(1))) unsigned int*)g,
        (__attribute__((address_space(3))) unsigned int*)l,
        16, 0, 0);
}

// ---------------- K0: cast X f32 -> bf16 (1 float4 per thread, fully coalesced) ----
__global__ void cast_x(const float* __restrict__ x, unsigned short* __restrict__ xb) {
    long i = ((long)blockIdx.x * blockDim.x + threadIdx.x) * 4;
    float4 a = *(const float4*)(x + i);
    ushort4 o;
    o.x = f2bf(a.x); o.y = f2bf(a.y); o.z = f2bf(a.z); o.w = f2bf(a.w);
    *(ushort4*)(xb + i) = o;
}

// ---------------- K0b: Wy (D x DIM) f32 -> WyT (DIM x D) bf16 ----------------
__global__ void transpose_cast(const float* __restrict__ Wsrc, unsigned short* __restrict__ Wdst) {
    __shared__ float tile[32][33];
    int bx = blockIdx.x * 32;           // col (e) base
    int by = blockIdx.y * 32;           // row (d) base
    int tx = threadIdx.x & 31;
    int ty4 = (threadIdx.x >> 5) * 4;
    #pragma unroll
    for (int r = 0; r < 4; r++)
        tile[ty4 + r][tx] = Wsrc[(size_t)(by + ty4 + r) * DIMQ + bx + tx];
    __syncthreads();
    #pragma unroll
    for (int r = 0; r < 4; r++)
        Wdst[(size_t)(bx + ty4 + r) * DD + by + tx] = f2bf(tile[tx][ty4 + r]);
}

// ---------------- K1: dual vec-mat, weight-dedup form ----------------
// One block = (64 e-cols) x (16 batches) x (1 matrix). Weights are read
// 2x total (one per batch-chunk) instead of 32x: 256 MB -> 16 MB.
// Batch vectors staged in LDS (broadcast reads, conflict-free).
__global__ void vecmat2(const float* __restrict__ last,
                        const float* __restrict__ Wh, const float* __restrict__ Wx,
                        float* __restrict__ hproj, float* __restrict__ lsWx) {
    __shared__ float ls[16][1024];      // 64 KiB: 16 batch vectors
    __shared__ float red[4][16][64];    // 16 KiB: split-K partials
    int e0 = blockIdx.x * 64;
    int b0 = blockIdx.y * 16;
    const float* Mat = blockIdx.z ? Wx : Wh;
    float* outp = blockIdx.z ? lsWx : hproj;
    int tid = threadIdx.x;
    for (int idx = tid; idx < 16 * 1024; idx += 256)
        ls[idx >> 10][idx & 1023] = last[(size_t)(b0 + (idx >> 10)) * DD + (idx & 1023)];
    __syncthreads();
    int e = tid & 63, dg = tid >> 6;
    int d0 = dg * 256;
    float acc[16];
    #pragma unroll
    for (int b = 0; b < 16; b++) acc[b] = 0.f;
    const float* Mp = Mat + (size_t)d0 * DIMQ + e0 + e;
    #pragma unroll 4
    for (int d = 0; d < 256; d++) {
        float mv = Mp[(size_t)d * DIMQ];
        #pragma unroll
        for (int b = 0; b < 16; b++) acc[b] += ls[b][d0 + d] * mv;
    }
    #pragma unroll
    for (int b = 0; b < 16; b++) red[dg][b][e] = acc[b];
    __syncthreads();
    if (dg == 0) {
        #pragma unroll
        for (int b = 0; b < 16; b++) {
            float v = red[0][b][e] + red[1][b][e] + red[2][b][e] + red[3][b][e];
            outp[(size_t)(b0 + b) * DIMQ + e0 + e] = v;
        }
    }
}

// ---------------- K2: fused GEMM + relu·w reduce -> partial scores ----------------
// (unchanged from R5: 256x256 tile, BK=64, 8 waves, 2-phase/K-tile counted-vmcnt)
__global__ __launch_bounds__(512, 2)
void gemm_scores(const unsigned short* __restrict__ Xb,
                 const unsigned short* __restrict__ WyT,
                 const float* __restrict__ hproj,
                 const float* __restrict__ wvec,
                 float* __restrict__ partials) {
    // slot s: A at s*32768, B at s*32768+16384 (ushort idx); frag-ordered, 0 conflicts
    __shared__ unsigned short lds[65536];
    __shared__ float lp[256];

    int tid = threadIdx.x;
    int lane = tid & 63;
    int wave = tid >> 6;
    int wr = wave >> 2;          // 0..1  (M half: rows wr*128..+127)
    int wc = wave & 3;           // 0..3  (N quarter: cols wc*64..+63)

    // --- XCD-grouping swizzle: put the 4 ntile-siblings (same X-panel) on one XCD ---
    int bidx = blockIdx.x;
    int rr = bidx & 255, rnd = bidx >> 8;       // 4 rounds of 256 blocks
    int xcd = rr & 7, slot = rr >> 3;           // hw dispatch round-robins XCDs
    int ntile = slot & 3;
    int mtile = rnd * 64 + xcd * 8 + (slot >> 2);

    if (tid < 256) lp[tid] = 0.f;

    // staging: wave w stages chunk groups (sub=w>>1, ks=w&1) and (sub+4, ks)
    int ssub = wave >> 1, sks = wave & 1;
    const unsigned short* aG = Xb  + (size_t)(mtile * 256 + ssub * 16 + (lane & 15)) * DD + sks * 32 + (lane >> 4) * 8;
    const unsigned short* bG = WyT + (size_t)(ntile * 256 + ssub * 16 + (lane & 15)) * DD + sks * 32 + (lane >> 4) * 8;
    unsigned short* ldsAst = &lds[(ssub * 128 + sks * 64 + lane) * 8];
    unsigned short* ldsBst = ldsAst + 16384;

    // read bases (ushort units)
    const unsigned short* aRd = &lds[wr * 8192 + lane * 8];
    const unsigned short* bRd = &lds[16384 + (wc >> 1) * 8192 + (wc & 1) * 4096 + lane * 8];

#define STAGE_A(S_, H_, T_) { \
    const unsigned short* g_ = aG + (size_t)(H_) * 131072 + (T_) * 64; \
    load_lds16(g_,         ldsAst + (S_) * 32768 + (H_) * 8192);       \
    load_lds16(g_ + 65536, ldsAst + (S_) * 32768 + (H_) * 8192 + 4096); }
#define STAGE_B(S_, H_, T_) { \
    const unsigned short* g_ = bG + (size_t)(H_) * 131072 + (T_) * 64; \
    load_lds16(g_,         ldsBst + (S_) * 32768 + (H_) * 8192);       \
    load_lds16(g_ + 65536, ldsBst + (S_) * 32768 + (H_) * 8192 + 4096); }
#define STAGE_TILE(S_, T_) { STAGE_A(S_, 0, T_); STAGE_A(S_, 1, T_); \
                             STAGE_B(S_, 0, T_); STAGE_B(S_, 1, T_); }

    f32x4 acc[8][4] = {};
    bf16x8 af[4][2], bfr[4][2];

#define LDA(S_, MH) { \
    _Pragma("unroll") for (int i_ = 0; i_ < 4; i_++) \
    _Pragma("unroll") for (int k_ = 0; k_ < 2; k_++) \
        af[i_][k_] = *reinterpret_cast<const bf16x8*>(aRd + (S_) * 32768 + ((MH) * 4 + i_) * 1024 + k_ * 512); }
#define LDB(S_, NH) { \
    _Pragma("unroll") for (int j_ = 0; j_ < 2; j_++) \
    _Pragma("unroll") for (int k_ = 0; k_ < 2; k_++) \
        bfr[(NH) * 2 + j_][k_] = *reinterpret_cast<const bf16x8*>(bRd + (S_) * 32768 + ((NH) * 2 + j_) * 1024 + k_ * 512); }
#define MFMA_Q(MH, NH) { \
    _Pragma("unroll") for (int k_ = 0; k_ < 2; k_++) \
    _Pragma("unroll") for (int i_ = 0; i_ < 4; i_++) \
    _Pragma("unroll") for (int j_ = 0; j_ < 2; j_++) \
        acc[(MH) * 4 + i_][(NH) * 2 + j_] = __builtin_amdgcn_mfma_f32_16x16x32_bf16( \
            af[i_][k_], bfr[(NH) * 2 + j_][k_], acc[(MH) * 4 + i_][(NH) * 2 + j_], 0, 0, 0); }

#define BAR() __builtin_amdgcn_s_barrier()
#define LGKM0() asm volatile("s_waitcnt lgkmcnt(0)" ::: "memory")
#define VMW8() asm volatile("s_waitcnt vmcnt(8)" ::: "memory")
#define PRIO1() __builtin_amdgcn_s_setprio(1)
#define PRIO0() __builtin_amdgcn_s_setprio(0)

    // prologue: stage tile0 -> slot0, tile1 -> slot1 (16 loads outstanding)
    STAGE_TILE(0, 0);
    STAGE_TILE(1, 1);

    #pragma unroll 2
    for (int t = 0; t < 16; ++t) {
        int s = t & 1;
        int tp = (t + 2 > 15) ? 15 : (t + 2);   // tail re-stage (L2-hot, never read)

        VMW8();                 // tile t's 8 loads landed (newest 8 = tile t+1's)
        BAR();                  // slot s valid for every wave

        LDB(s, 0); LDB(s, 1);   // 8 ds_read_b128: all B frags
        LDA(s, 0);              // 8 ds_read_b128: A frags, M-half 0
        PRIO1(); MFMA_Q(0, 0); MFMA_Q(0, 1); PRIO0();   // 32 MFMA (compiler lgkm-waits)

        LDA(s, 1);              // 8 ds_read_b128: A frags, M-half 1
        LGKM0();                // my reads complete -> my regs hold slot s data
        BAR();                  // ALL waves done reading slot s -> slot dead

        STAGE_TILE(s, tp);      // 8 DMA into slot s; flight overlaps MFMA below
        PRIO1(); MFMA_Q(1, 0); MFMA_Q(1, 1); PRIO0();   // 32 MFMA
    }

    __syncthreads();   // drains trailing prefetches; epilogue uses lp only

    // Epilogue: partial score = sum_n relu(acc + hproj[b,n]) * w[n]
    int bIdx = mtile >> 3;                    // 8 mtiles per batch row-block
    int q = lane >> 4, l15 = lane & 15;

    float hpv[4], wvv[4];
    #pragma unroll
    for (int nf = 0; nf < 4; nf++) {
        int n = ntile * 256 + wc * 64 + nf * 16 + l15;
        hpv[nf] = hproj[bIdx * DIMQ + n];
        wvv[nf] = wvec[n];
    }

    #pragma unroll
    for (int m = 0; m < 8; m++) {
        f32x4 s = {0.f, 0.f, 0.f, 0.f};
        #pragma unroll
        for (int nf = 0; nf < 4; nf++) {
            #pragma unroll
            for (int r = 0; r < 4; r++) {
                float v = acc[m][nf][r] + hpv[nf];
                v = v > 0.f ? v : 0.f;
                s[r] += v * wvv[nf];
            }
        }
        #pragma unroll
        for (int off = 1; off < 16; off <<= 1) {
            s[0] += __shfl_xor(s[0], off);
            s[1] += __shfl_xor(s[1], off);
            s[2] += __shfl_xor(s[2], off);
            s[3] += __shfl_xor(s[3], off);
        }
        if (l15 == 0) {
            int mrow = wr * 128 + m * 16 + q * 4;
            atomicAdd(&lp[mrow + 0], s[0]);
            atomicAdd(&lp[mrow + 1], s[1]);
            atomicAdd(&lp[mrow + 2], s[2]);
            atomicAdd(&lp[mrow + 3], s[3]);
        }
    }
    __syncthreads();
    if (tid < 256)
        partials[(size_t)ntile * MTOT + mtile * 256 + tid] = lp[tid];

#undef STAGE_A
#undef STAGE_B
#undef STAGE_TILE
#undef LDA
#undef LDB
#undef MFMA_Q
#undef BAR
#undef LGKM0
#undef VMW8
#undef PRIO1
#undef PRIO0
}

// ---------------- K3: fused partial-sum + softmax over T (512 threads) ----------------
__global__ void softmax_alpha(const float* __restrict__ partials, float* __restrict__ alpha) {
    __shared__ float wred[8];
    __shared__ float wsum[8];
    int b = blockIdx.x;
    int tid = threadIdx.x;
    float s[4];
    float mx = -1e30f;
    #pragma unroll
    for (int c = 0; c < 4; c++) {
        int t = b * TT + tid + c * 512;
        float v = 0.f;
        #pragma unroll
        for (int p = 0; p < 4; p++) v += partials[(size_t)p * MTOT + t];
        s[c] = v;
        mx = fmaxf(mx, v);
    }
    for (int off = 32; off; off >>= 1) mx = fmaxf(mx, __shfl_xor(mx, off));
    if ((tid & 63) == 0) wred[tid >> 6] = mx;
    __syncthreads();
    mx = wred[0];
    #pragma unroll
    for (int wv = 1; wv < 8; wv++) mx = fmaxf(mx, wred[wv]);
    float sum = 0.f;
    #pragma unroll
    for (int c = 0; c < 4; c++) { s[c] = expf(s[c] - mx); sum += s[c]; }
    for (int off = 32; off; off >>= 1) sum += __shfl_xor(sum, off);
    if ((tid & 63) == 0) wsum[tid >> 6] = sum;
    __syncthreads();
    sum = 0.f;
    #pragma unroll
    for (int wv = 0; wv < 8; wv++) sum += wsum[wv];
    float inv = 1.f / sum;
    #pragma unroll
    for (int c = 0; c < 4; c++) alpha[b * TT + tid + c * 512] = s[c] * inv;
}

// ---------------- K4: r_part[tc][b][d] = sum_{t in 128-chunk} alpha * X ----------------
__global__ void weighted_sum(const unsigned short* __restrict__ Xb,
                             const float* __restrict__ alpha,
                             float* __restrict__ r_part) {
    __shared__ float al[128];
    int tc = blockIdx.x, b = blockIdx.y, tid = threadIdx.x;
    if (tid < 128) al[tid] = alpha[b * TT + tc * 128 + tid];
    __syncthreads();
    int d0 = tid * 4;
    const unsigned short* base = Xb + ((size_t)(b * TT + tc * 128)) * DD + d0;
    f32x4 acc = {0.f, 0.f, 0.f, 0.f};
    #pragma unroll 2
    for (int t = 0; t < 128; t++) {
        ushort4 xv = *(const ushort4*)(base + (size_t)t * DD);
        float a_ = al[t];
        acc[0] += a_ * bf2f(xv.x);
        acc[1] += a_ * bf2f(xv.y);
        acc[2] += a_ * bf2f(xv.z);
        acc[3] += a_ * bf2f(xv.w);
    }
    float* o = r_part + ((size_t)tc * BB + b) * DD + d0;
    *(float4*)o = *(float4*)&acc;
}

// ---------------- K5: out = relu(r @ Wp + lsWx), weight-dedup form ----------------
// One block = (64 e-cols) x (16 batches). Wp read 2x total instead of 32x.
__global__ void final_out(const float* __restrict__ r_part, const float* __restrict__ Wp,
                          const float* __restrict__ lsWx, float* __restrict__ out) {
    __shared__ float rs[16][1024];      // 64 KiB: 16 reduced r vectors
    __shared__ float red[4][16][64];    // 16 KiB
    int e0 = blockIdx.x * 64;
    int b0 = blockIdx.y * 16;
    int tid = threadIdx.x;
    for (int idx = tid; idx < 16 * 1024; idx += 256) {
        int b = idx >> 10, d = idx & 1023;
        float v = 0.f;
        #pragma unroll
        for (int p = 0; p < 16; p++)
            v += r_part[((size_t)p * BB + b0 + b) * DD + d];
        rs[b][d] = v;
    }
    __syncthreads();
    int e = tid & 63, dg = tid >> 6;
    int d0 = dg * 256;
    float acc[16];
    #pragma unroll
    for (int b = 0; b < 16; b++) acc[b] = 0.f;
    const float* Mp = Wp + (size_t)d0 * DIMQ + e0 + e;
    #pragma unroll 4
    for (int d = 0; d < 256; d++) {
        float mv = Mp[(size_t)d * DIMQ];
        #pragma unroll
        for (int b = 0; b < 16; b++) acc[b] += rs[b][d0 + d] * mv;
    }
    #pragma unroll
    for (int b = 0; b < 16; b++) red[dg][b][e] = acc[b];
    __syncthreads();
    if (dg == 0) {
        #pragma unroll
        for (int b = 0; b < 16; b++) {
            float v = red[0][b][e] + red[1][b][e] + red[2][b][e] + red[3][b][e]
                    + lsWx[(size_t)(b0 + b) * DIMQ + e0 + e];
            out[(size_t)(b0 + b) * DIMQ + e0 + e] = fmaxf(v, 0.f);
        }
    }
}

extern "C" void kernel_launch(void* const* d_in, const int* in_sizes, int n_in,
                              void* d_out, int out_size, void* d_ws, size_t ws_size,
                              hipStream_t stream) {
    const float* x    = (const float*)d_in[0];  // (B,T,D)
    const float* last = (const float*)d_in[1];  // (B,D)
    const float* Wy   = (const float*)d_in[2];  // (D,DIM)
    const float* Wh   = (const float*)d_in[3];  // (D,DIM)
    const float* w    = (const float*)d_in[4];  // (DIM,1)
    const float* Wp   = (const float*)d_in[5];  // (D,DIM)
    const float* Wx   = (const float*)d_in[6];  // (D,DIM)
    float* out = (float*)d_out;

    // workspace layout (~134 MiB)
    char* ws = (char*)d_ws;
    unsigned short* Xb   = (unsigned short*)(ws);                  // 128 MiB
    unsigned short* WyT  = (unsigned short*)(ws + 134217728);      // 2 MiB
    float* hproj         = (float*)(ws + 136314880);               // 128 KiB
    float* lsWx          = (float*)(ws + 136445952);               // 128 KiB
    float* partials      = (float*)(ws + 136577024);               // 1 MiB (4 x 65536)
    float* alpha         = (float*)(ws + 137625600);               // 256 KiB
    float* r_part        = (float*)(ws + 137887744);               // 2 MiB (16 x 32 x 1024)

    cast_x<<<BB*TT*DD/4/256, 256, 0, stream>>>(x, Xb);
    transpose_cast<<<dim3(32, 32), 256, 0, stream>>>(Wy, WyT);
    vecmat2<<<dim3(DIMQ/64, 2, 2), 256, 0, stream>>>(last, Wh, Wx, hproj, lsWx);
    gemm_scores<<<1024, 512, 0, stream>>>(Xb, WyT, hproj, w, partials);
    softmax_alpha<<<BB, 512, 0, stream>>>(partials, alpha);
    weighted_sum<<<dim3(TT/128, BB), 256, 0, stream>>>(Xb, alpha, r_part);
    final_out<<<dim3(DIMQ/64, 2), 256, 0, stream>>>(r_part, Wp, lsWx, out);
}

// Round 7
// 667.680 us; speedup vs baseline: 1.0373x; 1.0373x over previous
//
#include <hip/hip_runtime.h>
#include <hip/hip_bf16.h>
#include <stdint.h>

// Problem dims (fixed)
#define BB 32
#define TT 2048
#define DD 1024
#define DIMQ 1024
#define MTOT (BB*TT)   // 65536 rows of X flattened

typedef __attribute__((ext_vector_type(8))) __bf16 bf16x8;
typedef __attribute__((ext_vector_type(4))) float f32x4;

__device__ __forceinline__ unsigned short f2bf(float f) {
    unsigned int u = __float_as_uint(f);
    u += 0x7FFF + ((u >> 16) & 1);   // round-to-nearest-even
    return (unsigned short)(u >> 16);
}

__device__ __forceinline__ void load_lds16(const void* g, void* l) {
    __builtin_amdgcn_global_load_lds(
        (const __attribute__((address_space(1))) unsigned int*)g,
        (__attribute__((address_space(3))) unsigned int*)l,
        16, 0, 0);
}

// ---------------- K0b: Wy (D x DIM) f32 -> WyT (DIM x D) bf16 ----------------
__global__ void transpose_cast(const float* __restrict__ Wsrc, unsigned short* __restrict__ Wdst) {
    __shared__ float tile[32][33];
    int bx = blockIdx.x * 32;           // col (e) base
    int by = blockIdx.y * 32;           // row (d) base
    int tx = threadIdx.x & 31;
    int ty4 = (threadIdx.x >> 5) * 4;
    #pragma unroll
    for (int r = 0; r < 4; r++)
        tile[ty4 + r][tx] = Wsrc[(size_t)(by + ty4 + r) * DIMQ + bx + tx];
    __syncthreads();
    #pragma unroll
    for (int r = 0; r < 4; r++)
        Wdst[(size_t)(bx + ty4 + r) * DD + by + tx] = f2bf(tile[tx][ty4 + r]);
}

// ---------------- K1: fused dual vec-mat, split-K (R5 form — measurement-backed) ----
__global__ void vecmat2(const float* __restrict__ last,
                        const float* __restrict__ Wh, const float* __restrict__ Wx,
                        float* __restrict__ hproj, float* __restrict__ lsWx) {
    __shared__ float vs[DD];
    __shared__ float red[4][64];
    int b = blockIdx.y;
    int e0 = blockIdx.x * 64;
    const float* Mat = blockIdx.z ? Wx : Wh;
    float* outp = blockIdx.z ? lsWx : hproj;
    int tid = threadIdx.x;
    for (int d = tid; d < DD; d += 256) vs[d] = last[b * DD + d];
    __syncthreads();
    int e = tid & 63, dg = tid >> 6;
    int d0 = dg * 256;
    const float* Mp = Mat + (size_t)d0 * DIMQ + e0 + e;
    float acc = 0.f;
    #pragma unroll 8
    for (int d = 0; d < 256; d++) acc += vs[d0 + d] * Mp[(size_t)d * DIMQ];
    red[dg][e] = acc;
    __syncthreads();
    if (dg == 0)
        outp[b * DIMQ + e0 + e] = red[0][e] + red[1][e] + red[2][e] + red[3][e];
}

// ---------------- K2: fused GEMM + relu·w reduce -> partial scores ----------------
// 256x256 tile, BK=64, 8 waves, 128 KiB dbuf LDS, 2-phase counted-vmcnt schedule
// (R5 structure). NEW: A-operand read directly from f32 X via 2-deep reg pipeline
// (8 float4/thread/tile) -> v_cvt_pk_bf16_f32 -> ds_write_b128 into the UNCHANGED
// LDS layout. Kills the separate cast_x pass (384 MB stream) and the Xb workspace.
// vmem ops/tile = 8 A-reg-loads + 4 B-DMA = 12; per-iter issue order: A(t+3) then
// B(t+2), so compiler's A-wait at AWRITE is vmcnt(4) (keeps B(t+1) in flight) and
// our VMW(12) drains exactly B(t) before the tile-valid barrier.
__global__ __launch_bounds__(512, 2)
void gemm_scores(const float* __restrict__ Xf,
                 const unsigned short* __restrict__ WyT,
                 const float* __restrict__ hproj,
                 const float* __restrict__ wvec,
                 float* __restrict__ partials) {
    // slot s: A at s*32768, B at s*32768+16384 (ushort idx); frag-ordered, 0 conflicts
    __shared__ unsigned short lds[65536];
    __shared__ float lp[256];

    int tid = threadIdx.x;
    int lane = tid & 63;
    int wave = tid >> 6;
    int wr = wave >> 2;          // 0..1  (M half: rows wr*128..+127)
    int wc = wave & 3;           // 0..3  (N quarter: cols wc*64..+63)

    // --- XCD-grouping swizzle: 4 ntile-siblings (same X-panel) on one XCD ---
    int bidx = blockIdx.x;
    int rr = bidx & 255, rnd = bidx >> 8;
    int xcd = rr & 7, slot = rr >> 3;
    int ntile = slot & 3;
    int mtile = rnd * 64 + xcd * 8 + (slot >> 2);

    if (tid < 256) lp[tid] = 0.f;

    // staging coords: wave w handles (sub=w>>1, ks=w&1) rows ssub*16+(lane&15)
    int ssub = wave >> 1, sks = wave & 1;
    // f32 A source base for this thread
    const float* aF = Xf + (size_t)(mtile * 256 + ssub * 16 + (lane & 15)) * DD
                    + sks * 32 + (lane >> 4) * 8;
    // B source (bf16 WyT) — unchanged DMA path
    const unsigned short* bG = WyT + (size_t)(ntile * 256 + ssub * 16 + (lane & 15)) * DD
                             + sks * 32 + (lane >> 4) * 8;
    unsigned short* ldsAst = &lds[(ssub * 128 + sks * 64 + lane) * 8];
    unsigned short* ldsBst = ldsAst + 16384;

    // read bases (ushort units) — unchanged
    const unsigned short* aRd = &lds[wr * 8192 + lane * 8];
    const unsigned short* bRd = &lds[16384 + (wc >> 1) * 8192 + (wc & 1) * 4096 + lane * 8];

    float4 rA0[8], rA1[8];   // two A reg sets (even/odd tiles), 32 VGPR each

// issue 8 float4 loads of A K-tile T_ into reg set RS (q: H=q>>2, p=(q>>1)&1, h=q&1)
#define AISSUE(RS, T_) { \
    _Pragma("unroll") for (int q_ = 0; q_ < 8; q_++) { \
        int H_ = q_ >> 2, p_ = (q_ >> 1) & 1, h_ = q_ & 1; \
        RS[q_] = *reinterpret_cast<const float4*>( \
            aF + (size_t)(H_ * 128 + p_ * 64) * DD + (T_) * 64 + h_ * 4); } }

// convert + ds_write reg set RS into LDS slot S_ (4 x ds_write_b128)
#define AWRITE(RS, S_) { \
    _Pragma("unroll") for (int c_ = 0; c_ < 4; c_++) { \
        unsigned int u0_, u1_, u2_, u3_; \
        asm volatile("v_cvt_pk_bf16_f32 %0, %1, %2" : "=v"(u0_) : "v"(RS[c_*2].x),   "v"(RS[c_*2].y)); \
        asm volatile("v_cvt_pk_bf16_f32 %0, %1, %2" : "=v"(u1_) : "v"(RS[c_*2].z),   "v"(RS[c_*2].w)); \
        asm volatile("v_cvt_pk_bf16_f32 %0, %1, %2" : "=v"(u2_) : "v"(RS[c_*2+1].x), "v"(RS[c_*2+1].y)); \
        asm volatile("v_cvt_pk_bf16_f32 %0, %1, %2" : "=v"(u3_) : "v"(RS[c_*2+1].z), "v"(RS[c_*2+1].w)); \
        uint4 pk_; pk_.x = u0_; pk_.y = u1_; pk_.z = u2_; pk_.w = u3_; \
        int H_ = c_ >> 1, p_ = c_ & 1; \
        *reinterpret_cast<uint4*>(ldsAst + (S_) * 32768 + H_ * 8192 + p_ * 4096) = pk_; } }

#define BSTAGE(S_, T_) { \
    { const unsigned short* g_ = bG + (T_) * 64; \
      load_lds16(g_,         ldsBst + (S_) * 32768); \
      load_lds16(g_ + 65536, ldsBst + (S_) * 32768 + 4096); } \
    { const unsigned short* g_ = bG + (size_t)131072 + (T_) * 64; \
      load_lds16(g_,         ldsBst + (S_) * 32768 + 8192); \
      load_lds16(g_ + 65536, ldsBst + (S_) * 32768 + 8192 + 4096); } }

    f32x4 acc[8][4] = {};
    bf16x8 af[4][2], bfr[4][2];

#define LDA(S_, MH) { \
    _Pragma("unroll") for (int i_ = 0; i_ < 4; i_++) \
    _Pragma("unroll") for (int k_ = 0; k_ < 2; k_++) \
        af[i_][k_] = *reinterpret_cast<const bf16x8*>(aRd + (S_) * 32768 + ((MH) * 4 + i_) * 1024 + k_ * 512); }
#define LDB(S_, NH) { \
    _Pragma("unroll") for (int j_ = 0; j_ < 2; j_++) \
    _Pragma("unroll") for (int k_ = 0; k_ < 2; k_++) \
        bfr[(NH) * 2 + j_][k_] = *reinterpret_cast<const bf16x8*>(bRd + (S_) * 32768 + ((NH) * 2 + j_) * 1024 + k_ * 512); }
#define MFMA_Q(MH, NH) { \
    _Pragma("unroll") for (int k_ = 0; k_ < 2; k_++) \
    _Pragma("unroll") for (int i_ = 0; i_ < 4; i_++) \
    _Pragma("unroll") for (int j_ = 0; j_ < 2; j_++) \
        acc[(MH) * 4 + i_][(NH) * 2 + j_] = __builtin_amdgcn_mfma_f32_16x16x32_bf16( \
            af[i_][k_], bfr[(NH) * 2 + j_][k_], acc[(MH) * 4 + i_][(NH) * 2 + j_], 0, 0, 0); }

#define BAR() __builtin_amdgcn_s_barrier()
#define LGKM0() asm volatile("s_waitcnt lgkmcnt(0)" ::: "memory")
#define VMW12() asm volatile("s_waitcnt vmcnt(12)" ::: "memory")
#define PRIO1() __builtin_amdgcn_s_setprio(1)
#define PRIO0() __builtin_amdgcn_s_setprio(0)

    // ---- prologue: A(0),A(1) regs -> LDS; B(0),B(1) DMA; A(2) in flight ----
    AISSUE(rA0, 0);
    AISSUE(rA1, 1);
    AWRITE(rA0, 0);      // compiler waits A(0) (A(1) stays in flight)
    BSTAGE(0, 0);
    AWRITE(rA1, 1);      // compiler waits A(1) (B(0) stays in flight)
    AISSUE(rA0, 2);
    BSTAGE(1, 1);
    LGKM0();             // my ds_writes drained before first barrier
    // outstanding: A(2)=8 + B(1)=4 (B(0) may still fly; VMW12 in iter0 drains it)

// one K-tile iteration; T_ must have compile-time-known parity (s = T_&1).
// SA_ = reg set holding A(T_+2) (parity T_&1); SB_ = other set (gets A(T_+3)).
#define ITER(T_, SA_, SB_) { \
    const int s_ = (T_) & 1; \
    int tpa_ = (T_) + 3; if (tpa_ > 15) tpa_ = 15; \
    int tpb_ = (T_) + 2; if (tpb_ > 15) tpb_ = 15; \
    VMW12();            /* tile T_'s B landed; A(T_+2)+B(T_+1) stay in flight */ \
    BAR();              /* slot s_ valid for every wave */ \
    LDB(s_, 0); LDB(s_, 1); \
    LDA(s_, 0); \
    PRIO1(); MFMA_Q(0, 0); MFMA_Q(0, 1); PRIO0(); \
    LDA(s_, 1); \
    LGKM0();            /* my reads done -> regs hold slot data */ \
    BAR();              /* all waves done reading slot s_ -> slot dead */ \
    AWRITE(SA_, s_);    /* A(T_+2) -> slot s_ (compiler vmcnt(4) keeps B(T_+1)) */ \
    AISSUE(SB_, tpa_);  /* A(T_+3) into freed set */ \
    BSTAGE(s_, tpb_);   /* B(T_+2) DMA -> slot s_ */ \
    PRIO1(); MFMA_Q(1, 0); MFMA_Q(1, 1); PRIO0(); }

    for (int tt = 0; tt < 8; ++tt) {
        ITER(2 * tt,     rA0, rA1);
        ITER(2 * tt + 1, rA1, rA0);
    }

    __syncthreads();   // drains trailing prefetches; epilogue uses lp only

    // Epilogue: partial score = sum_n relu(acc + hproj[b,n]) * w[n]
    int bIdx = mtile >> 3;                    // 8 mtiles per batch row-block
    int q = lane >> 4, l15 = lane & 15;

    float hpv[4], wvv[4];
    #pragma unroll
    for (int nf = 0; nf < 4; nf++) {
        int n = ntile * 256 + wc * 64 + nf * 16 + l15;
        hpv[nf] = hproj[bIdx * DIMQ + n];
        wvv[nf] = wvec[n];
    }

    #pragma unroll
    for (int m = 0; m < 8; m++) {
        f32x4 s = {0.f, 0.f, 0.f, 0.f};
        #pragma unroll
        for (int nf = 0; nf < 4; nf++) {
            #pragma unroll
            for (int r = 0; r < 4; r++) {
                float v = acc[m][nf][r] + hpv[nf];
                v = v > 0.f ? v : 0.f;
                s[r] += v * wvv[nf];
            }
        }
        #pragma unroll
        for (int off = 1; off < 16; off <<= 1) {
            s[0] += __shfl_xor(s[0], off);
            s[1] += __shfl_xor(s[1], off);
            s[2] += __shfl_xor(s[2], off);
            s[3] += __shfl_xor(s[3], off);
        }
        if (l15 == 0) {
            int mrow = wr * 128 + m * 16 + q * 4;
            atomicAdd(&lp[mrow + 0], s[0]);
            atomicAdd(&lp[mrow + 1], s[1]);
            atomicAdd(&lp[mrow + 2], s[2]);
            atomicAdd(&lp[mrow + 3], s[3]);
        }
    }
    __syncthreads();
    if (tid < 256)
        partials[(size_t)ntile * MTOT + mtile * 256 + tid] = lp[tid];

#undef AISSUE
#undef AWRITE
#undef BSTAGE
#undef LDA
#undef LDB
#undef MFMA_Q
#undef BAR
#undef LGKM0
#undef VMW12
#undef PRIO1
#undef PRIO0
#undef ITER
}

// ---------------- K3: fused partial-sum + softmax over T (R5 form) ----------------
__global__ void softmax_alpha(const float* __restrict__ partials, float* __restrict__ alpha) {
    __shared__ float wred[4];
    __shared__ float wsum[4];
    int b = blockIdx.x;
    int tid = threadIdx.x;
    float s[8];
    float mx = -1e30f;
    #pragma unroll
    for (int c = 0; c < 8; c++) {
        int t = b * TT + tid + c * 256;
        float v = 0.f;
        #pragma unroll
        for (int p = 0; p < 4; p++) v += partials[(size_t)p * MTOT + t];
        s[c] = v;
        mx = fmaxf(mx, v);
    }
    for (int off = 32; off; off >>= 1) mx = fmaxf(mx, __shfl_xor(mx, off));
    if ((tid & 63) == 0) wred[tid >> 6] = mx;
    __syncthreads();
    mx = fmaxf(fmaxf(wred[0], wred[1]), fmaxf(wred[2], wred[3]));
    float sum = 0.f;
    #pragma unroll
    for (int c = 0; c < 8; c++) { s[c] = expf(s[c] - mx); sum += s[c]; }
    for (int off = 32; off; off >>= 1) sum += __shfl_xor(sum, off);
    if ((tid & 63) == 0) wsum[tid >> 6] = sum;
    __syncthreads();
    sum = wsum[0] + wsum[1] + wsum[2] + wsum[3];
    float inv = 1.f / sum;
    #pragma unroll
    for (int c = 0; c < 8; c++) alpha[b * TT + tid + c * 256] = s[c] * inv;
}

// ---------------- K4: r_part[tc][b][d] = sum_{t in 128-chunk} alpha * X (f32 X) ----
__global__ void weighted_sum(const float* __restrict__ Xf,
                             const float* __restrict__ alpha,
                             float* __restrict__ r_part) {
    __shared__ float al[128];
    int tc = blockIdx.x, b = blockIdx.y, tid = threadIdx.x;
    if (tid < 128) al[tid] = alpha[b * TT + tc * 128 + tid];
    __syncthreads();
    int d0 = tid * 4;
    const float* base = Xf + ((size_t)(b * TT + tc * 128)) * DD + d0;
    f32x4 acc = {0.f, 0.f, 0.f, 0.f};
    #pragma unroll 2
    for (int t = 0; t < 128; t++) {
        float4 xv = *(const float4*)(base + (size_t)t * DD);
        float a_ = al[t];
        acc[0] += a_ * xv.x;
        acc[1] += a_ * xv.y;
        acc[2] += a_ * xv.z;
        acc[3] += a_ * xv.w;
    }
    float* o = r_part + ((size_t)tc * BB + b) * DD + d0;
    *(float4*)o = *(float4*)&acc;
}

// ---------------- K5: out = relu(r @ Wp + lsWx), fused r-reduce + split-K (R5 form) ----
__global__ void final_out(const float* __restrict__ r_part, const float* __restrict__ Wp,
                          const float* __restrict__ lsWx, float* __restrict__ out) {
    __shared__ float rs[DD];
    __shared__ float red[4][64];
    int b = blockIdx.y;
    int e0 = blockIdx.x * 64;
    int tid = threadIdx.x;
    for (int d = tid; d < DD; d += 256) {
        float v = 0.f;
        #pragma unroll
        for (int p = 0; p < 16; p++) v += r_part[((size_t)p * BB + b) * DD + d];
        rs[d] = v;
    }
    __syncthreads();
    int e = tid & 63, dg = tid >> 6;
    int d0 = dg * 256;
    const float* Mp = Wp + (size_t)d0 * DIMQ + e0 + e;
    float acc = 0.f;
    #pragma unroll 8
    for (int d = 0; d < 256; d++) acc += rs[d0 + d] * Mp[(size_t)d * DIMQ];
    red[dg][e] = acc;
    __syncthreads();
    if (dg == 0) {
        float v = red[0][e] + red[1][e] + red[2][e] + red[3][e]
                + lsWx[b * DIMQ + e0 + e];
        out[b * DIMQ + e0 + e] = fmaxf(v, 0.f);
    }
}

extern "C" void kernel_launch(void* const* d_in, const int* in_sizes, int n_in,
                              void* d_out, int out_size, void* d_ws, size_t ws_size,
                              hipStream_t stream) {
    const float* x    = (const float*)d_in[0];  // (B,T,D)
    const float* last = (const float*)d_in[1];  // (B,D)
    const float* Wy   = (const float*)d_in[2];  // (D,DIM)
    const float* Wh   = (const float*)d_in[3];  // (D,DIM)
    const float* w    = (const float*)d_in[4];  // (DIM,1)
    const float* Wp   = (const float*)d_in[5];  // (D,DIM)
    const float* Wx   = (const float*)d_in[6];  // (D,DIM)
    float* out = (float*)d_out;

    // workspace layout (Xb slot retired; offsets kept stable)
    char* ws = (char*)d_ws;
    unsigned short* WyT  = (unsigned short*)(ws + 134217728);      // 2 MiB
    float* hproj         = (float*)(ws + 136314880);               // 128 KiB
    float* lsWx          = (float*)(ws + 136445952);               // 128 KiB
    float* partials      = (float*)(ws + 136577024);               // 1 MiB (4 x 65536)
    float* alpha         = (float*)(ws + 137625600);               // 256 KiB
    float* r_part        = (float*)(ws + 137887744);               // 2 MiB (16 x 32 x 1024)

    transpose_cast<<<dim3(32, 32), 256, 0, stream>>>(Wy, WyT);
    vecmat2<<<dim3(DIMQ/64, BB, 2), 256, 0, stream>>>(last, Wh, Wx, hproj, lsWx);
    gemm_scores<<<1024, 512, 0, stream>>>(x, WyT, hproj, w, partials);
    softmax_alpha<<<BB, 256, 0, stream>>>(partials, alpha);
    weighted_sum<<<dim3(TT/128, BB), 256, 0, stream>>>(x, alpha, r_part);
    final_out<<<dim3(DIMQ/64, BB), 256, 0, stream>>>(r_part, Wp, lsWx, out);
}

// Round 10
// 654.922 us; speedup vs baseline: 1.0575x; 1.0195x over previous
//
#include <hip/hip_runtime.h>
#include <hip/hip_bf16.h>
#include <stdint.h>

// Problem dims (fixed)
#define BB 32
#define TT 2048
#define DD 1024
#define DIMQ 1024
#define MTOT (BB*TT)   // 65536 rows of X flattened

typedef __attribute__((ext_vector_type(8))) __bf16 bf16x8;
typedef __attribute__((ext_vector_type(4))) float f32x4;

__device__ __forceinline__ unsigned short f2bf(float f) {
    unsigned int u = __float_as_uint(f);
    u += 0x7FFF + ((u >> 16) & 1);   // round-to-nearest-even
    return (unsigned short)(u >> 16);
}

__device__ __forceinline__ void load_lds16(const void* g, void* l) {
    __builtin_amdgcn_global_load_lds(
        (const __attribute__((address_space(1))) unsigned int*)g,
        (__attribute__((address_space(3))) unsigned int*)l,
        16, 0, 0);
}

// ---------------- K0b: Wy (D x DIM) f32 -> WyT (DIM x D) bf16 ----------------
__global__ void transpose_cast(const float* __restrict__ Wsrc, unsigned short* __restrict__ Wdst) {
    __shared__ float tile[32][33];
    int bx = blockIdx.x * 32;           // col (e) base
    int by = blockIdx.y * 32;           // row (d) base
    int tx = threadIdx.x & 31;
    int ty4 = (threadIdx.x >> 5) * 4;
    #pragma unroll
    for (int r = 0; r < 4; r++)
        tile[ty4 + r][tx] = Wsrc[(size_t)(by + ty4 + r) * DIMQ + bx + tx];
    __syncthreads();
    #pragma unroll
    for (int r = 0; r < 4; r++)
        Wdst[(size_t)(bx + ty4 + r) * DD + by + tx] = f2bf(tile[tx][ty4 + r]);
}

// ---------------- K1: fused dual vec-mat, split-K (R5 form — measurement-backed) ----
__global__ void vecmat2(const float* __restrict__ last,
                        const float* __restrict__ Wh, const float* __restrict__ Wx,
                        float* __restrict__ hproj, float* __restrict__ lsWx) {
    __shared__ float vs[DD];
    __shared__ float red[4][64];
    int b = blockIdx.y;
    int e0 = blockIdx.x * 64;
    const float* Mat = blockIdx.z ? Wx : Wh;
    float* outp = blockIdx.z ? lsWx : hproj;
    int tid = threadIdx.x;
    for (int d = tid; d < DD; d += 256) vs[d] = last[b * DD + d];
    __syncthreads();
    int e = tid & 63, dg = tid >> 6;
    int d0 = dg * 256;
    const float* Mp = Mat + (size_t)d0 * DIMQ + e0 + e;
    float acc = 0.f;
    #pragma unroll 8
    for (int d = 0; d < 256; d++) acc += vs[d0 + d] * Mp[(size_t)d * DIMQ];
    red[dg][e] = acc;
    __syncthreads();
    if (dg == 0)
        outp[b * DIMQ + e0 + e] = red[0][e] + red[1][e] + red[2][e] + red[3][e];
}

// ---------------- K2: fused GEMM + relu·w reduce -> partial scores ----------------
// 256x256 tile, BK=64, 8 waves, 128 KiB dbuf LDS, 2-phase counted-vmcnt schedule.
// A-operand read directly from f32 X via SINGLE 8xfloat4 reg set (R7's two-set
// version spilled: 64 extra VGPRs blew the 256 unified budget at 2 waves/SIMD ->
// WRITE_SIZE 57.6MB scratch traffic). Single set keeps identical pipeline depth:
// iter t: AWRITE drains A(t+2) -> dead slot, then AISSUE reloads rA with A(t+3).
// Budget: 128 AGPR acc + 32 af + 32 bfr + 32 rA + ~25 addr ~= 249 <= 256.
// vmcnt: steady-state queue at iter top = B(t)4 + A(t+2)8 + B(t+1)4 = 16;
// VMW(12) drains exactly B(t); compiler's AWRITE wait is vmcnt(4) keeping B(t+1).
__global__ __launch_bounds__(512, 2)
void gemm_scores(const float* __restrict__ Xf,
                 const unsigned short* __restrict__ WyT,
                 const float* __restrict__ hproj,
                 const float* __restrict__ wvec,
                 float* __restrict__ partials) {
    // slot s: A at s*32768, B at s*32768+16384 (ushort idx); frag-ordered, 0 conflicts
    __shared__ unsigned short lds[65536];
    __shared__ float lp[256];

    int tid = threadIdx.x;
    int lane = tid & 63;
    int wave = tid >> 6;
    int wr = wave >> 2;          // 0..1  (M half: rows wr*128..+127)
    int wc = wave & 3;           // 0..3  (N quarter: cols wc*64..+63)

    // --- XCD-grouping swizzle: 4 ntile-siblings (same X-panel) on one XCD ---
    int bidx = blockIdx.x;
    int rr = bidx & 255, rnd = bidx >> 8;
    int xcd = rr & 7, slot = rr >> 3;
    int ntile = slot & 3;
    int mtile = rnd * 64 + xcd * 8 + (slot >> 2);

    if (tid < 256) lp[tid] = 0.f;

    // staging coords: wave w handles (sub=w>>1, ks=w&1) rows ssub*16+(lane&15)
    int ssub = wave >> 1, sks = wave & 1;
    const float* aF = Xf + (size_t)(mtile * 256 + ssub * 16 + (lane & 15)) * DD
                    + sks * 32 + (lane >> 4) * 8;
    const unsigned short* bG = WyT + (size_t)(ntile * 256 + ssub * 16 + (lane & 15)) * DD
                             + sks * 32 + (lane >> 4) * 8;
    unsigned short* ldsAst = &lds[(ssub * 128 + sks * 64 + lane) * 8];
    unsigned short* ldsBst = ldsAst + 16384;

    // read bases (ushort units) — unchanged
    const unsigned short* aRd = &lds[wr * 8192 + lane * 8];
    const unsigned short* bRd = &lds[16384 + (wc >> 1) * 8192 + (wc & 1) * 4096 + lane * 8];

    float4 rA[8];   // ONE A reg set (32 VGPR)

// issue 8 float4 loads of A K-tile T_ into rA (q: H=q>>2, p=(q>>1)&1, h=q&1)
#define AISSUE(T_) { \
    _Pragma("unroll") for (int q_ = 0; q_ < 8; q_++) { \
        int H_ = q_ >> 2, p_ = (q_ >> 1) & 1, h_ = q_ & 1; \
        rA[q_] = *reinterpret_cast<const float4*>( \
            aF + (size_t)(H_ * 128 + p_ * 64) * DD + (T_) * 64 + h_ * 4); } }

// convert + ds_write rA into LDS slot S_ (4 x ds_write_b128)
#define AWRITE(S_) { \
    _Pragma("unroll") for (int c_ = 0; c_ < 4; c_++) { \
        unsigned int u0_, u1_, u2_, u3_; \
        asm volatile("v_cvt_pk_bf16_f32 %0, %1, %2" : "=v"(u0_) : "v"(rA[c_*2].x),   "v"(rA[c_*2].y)); \
        asm volatile("v_cvt_pk_bf16_f32 %0, %1, %2" : "=v"(u1_) : "v"(rA[c_*2].z),   "v"(rA[c_*2].w)); \
        asm volatile("v_cvt_pk_bf16_f32 %0, %1, %2" : "=v"(u2_) : "v"(rA[c_*2+1].x), "v"(rA[c_*2+1].y)); \
        asm volatile("v_cvt_pk_bf16_f32 %0, %1, %2" : "=v"(u3_) : "v"(rA[c_*2+1].z), "v"(rA[c_*2+1].w)); \
        uint4 pk_; pk_.x = u0_; pk_.y = u1_; pk_.z = u2_; pk_.w = u3_; \
        int H_ = c_ >> 1, p_ = c_ & 1; \
        *reinterpret_cast<uint4*>(ldsAst + (S_) * 32768 + H_ * 8192 + p_ * 4096) = pk_; } }

#define BSTAGE(S_, T_) { \
    { const unsigned short* g_ = bG + (T_) * 64; \
      load_lds16(g_,         ldsBst + (S_) * 32768); \
      load_lds16(g_ + 65536, ldsBst + (S_) * 32768 + 4096); } \
    { const unsigned short* g_ = bG + (size_t)131072 + (T_) * 64; \
      load_lds16(g_,         ldsBst + (S_) * 32768 + 8192); \
      load_lds16(g_ + 65536, ldsBst + (S_) * 32768 + 8192 + 4096); } }

    f32x4 acc[8][4] = {};
    bf16x8 af[4][2], bfr[4][2];

#define LDA(S_, MH) { \
    _Pragma("unroll") for (int i_ = 0; i_ < 4; i_++) \
    _Pragma("unroll") for (int k_ = 0; k_ < 2; k_++) \
        af[i_][k_] = *reinterpret_cast<const bf16x8*>(aRd + (S_) * 32768 + ((MH) * 4 + i_) * 1024 + k_ * 512); }
#define LDB(S_, NH) { \
    _Pragma("unroll") for (int j_ = 0; j_ < 2; j_++) \
    _Pragma("unroll") for (int k_ = 0; k_ < 2; k_++) \
        bfr[(NH) * 2 + j_][k_] = *reinterpret_cast<const bf16x8*>(bRd + (S_) * 32768 + ((NH) * 2 + j_) * 1024 + k_ * 512); }
#define MFMA_Q(MH, NH) { \
    _Pragma("unroll") for (int k_ = 0; k_ < 2; k_++) \
    _Pragma("unroll") for (int i_ = 0; i_ < 4; i_++) \
    _Pragma("unroll") for (int j_ = 0; j_ < 2; j_++) \
        acc[(MH) * 4 + i_][(NH) * 2 + j_] = __builtin_amdgcn_mfma_f32_16x16x32_bf16( \
            af[i_][k_], bfr[(NH) * 2 + j_][k_], acc[(MH) * 4 + i_][(NH) * 2 + j_], 0, 0, 0); }

#define BAR() __builtin_amdgcn_s_barrier()
#define LGKM0() asm volatile("s_waitcnt lgkmcnt(0)" ::: "memory")
#define VMW12() asm volatile("s_waitcnt vmcnt(12)" ::: "memory")
#define PRIO1() __builtin_amdgcn_s_setprio(1)
#define PRIO0() __builtin_amdgcn_s_setprio(0)

    // ---- prologue: A(0),A(1) -> LDS via rA; B(0),B(1) DMA; A(2) in flight ----
    AISSUE(0);
    BSTAGE(0, 0);
    AWRITE(0);           // compiler waits A(0) (vmcnt(4): B(0) stays in flight)
    AISSUE(1);
    BSTAGE(1, 1);
    AWRITE(1);           // waits A(1) (drains B(0) as older; B(1) stays)
    AISSUE(2);
    LGKM0();             // my ds_writes drained before first barrier

    #pragma unroll 2
    for (int t = 0; t < 16; ++t) {
        int s = t & 1;
        int tpa = t + 3; if (tpa > 15) tpa = 15;   // tail re-issue (L2-hot, never used)
        int tpb = t + 2; if (tpb > 15) tpb = 15;

        VMW12();            // tile t's B landed; A(t+2)+B(t+1) stay in flight
        BAR();              // slot s valid for every wave

        LDB(s, 0); LDB(s, 1);
        LDA(s, 0);
        PRIO1(); MFMA_Q(0, 0); MFMA_Q(0, 1); PRIO0();
        LDA(s, 1);
        LGKM0();            // my reads done -> regs hold slot data
        BAR();              // all waves done reading slot s -> slot dead

        AWRITE(s);          // A(t+2) -> slot s (compiler vmcnt(4) keeps B(t+1))
        AISSUE(tpa);        // A(t+3) reuses rA (WAR ordered by compiler)
        BSTAGE(s, tpb);     // B(t+2) DMA -> slot s
        PRIO1(); MFMA_Q(1, 0); MFMA_Q(1, 1); PRIO0();
    }

    __syncthreads();   // drains trailing prefetches; epilogue uses lp only

    // Epilogue: partial score = sum_n relu(acc + hproj[b,n]) * w[n]
    int bIdx = mtile >> 3;                    // 8 mtiles per batch row-block
    int q = lane >> 4, l15 = lane & 15;

    float hpv[4], wvv[4];
    #pragma unroll
    for (int nf = 0; nf < 4; nf++) {
        int n = ntile * 256 + wc * 64 + nf * 16 + l15;
        hpv[nf] = hproj[bIdx * DIMQ + n];
        wvv[nf] = wvec[n];
    }

    #pragma unroll
    for (int m = 0; m < 8; m++) {
        f32x4 s = {0.f, 0.f, 0.f, 0.f};
        #pragma unroll
        for (int nf = 0; nf < 4; nf++) {
            #pragma unroll
            for (int r = 0; r < 4; r++) {
                float v = acc[m][nf][r] + hpv[nf];
                v = v > 0.f ? v : 0.f;
                s[r] += v * wvv[nf];
            }
        }
        #pragma unroll
        for (int off = 1; off < 16; off <<= 1) {
            s[0] += __shfl_xor(s[0], off);
            s[1] += __shfl_xor(s[1], off);
            s[2] += __shfl_xor(s[2], off);
            s[3] += __shfl_xor(s[3], off);
        }
        if (l15 == 0) {
            int mrow = wr * 128 + m * 16 + q * 4;
            atomicAdd(&lp[mrow + 0], s[0]);
            atomicAdd(&lp[mrow + 1], s[1]);
            atomicAdd(&lp[mrow + 2], s[2]);
            atomicAdd(&lp[mrow + 3], s[3]);
        }
    }
    __syncthreads();
    if (tid < 256)
        partials[(size_t)ntile * MTOT + mtile * 256 + tid] = lp[tid];

#undef AISSUE
#undef AWRITE
#undef BSTAGE
#undef LDA
#undef LDB
#undef MFMA_Q
#undef BAR
#undef LGKM0
#undef VMW12
#undef PRIO1
#undef PRIO0
}

// ---------------- K3: fused partial-sum + softmax over T (R5 form) ----------------
__global__ void softmax_alpha(const float* __restrict__ partials, float* __restrict__ alpha) {
    __shared__ float wred[4];
    __shared__ float wsum[4];
    int b = blockIdx.x;
    int tid = threadIdx.x;
    float s[8];
    float mx = -1e30f;
    #pragma unroll
    for (int c = 0; c < 8; c++) {
        int t = b * TT + tid + c * 256;
        float v = 0.f;
        #pragma unroll
        for (int p = 0; p < 4; p++) v += partials[(size_t)p * MTOT + t];
        s[c] = v;
        mx = fmaxf(mx, v);
    }
    for (int off = 32; off; off >>= 1) mx = fmaxf(mx, __shfl_xor(mx, off));
    if ((tid & 63) == 0) wred[tid >> 6] = mx;
    __syncthreads();
    mx = fmaxf(fmaxf(wred[0], wred[1]), fmaxf(wred[2], wred[3]));
    float sum = 0.f;
    #pragma unroll
    for (int c = 0; c < 8; c++) { s[c] = expf(s[c] - mx); sum += s[c]; }
    for (int off = 32; off; off >>= 1) sum += __shfl_xor(sum, off);
    if ((tid & 63) == 0) wsum[tid >> 6] = sum;
    __syncthreads();
    sum = wsum[0] + wsum[1] + wsum[2] + wsum[3];
    float inv = 1.f / sum;
    #pragma unroll
    for (int c = 0; c < 8; c++) alpha[b * TT + tid + c * 256] = s[c] * inv;
}

// ---------------- K4: r_part[tc][b][d] = sum_{t in 128-chunk} alpha * X (f32 X) ----
__global__ void weighted_sum(const float* __restrict__ Xf,
                             const float* __restrict__ alpha,
                             float* __restrict__ r_part) {
    __shared__ float al[128];
    int tc = blockIdx.x, b = blockIdx.y, tid = threadIdx.x;
    if (tid < 128) al[tid] = alpha[b * TT + tc * 128 + tid];
    __syncthreads();
    int d0 = tid * 4;
    const float* base = Xf + ((size_t)(b * TT + tc * 128)) * DD + d0;
    f32x4 acc = {0.f, 0.f, 0.f, 0.f};
    #pragma unroll 2
    for (int t = 0; t < 128; t++) {
        float4 xv = *(const float4*)(base + (size_t)t * DD);
        float a_ = al[t];
        acc[0] += a_ * xv.x;
        acc[1] += a_ * xv.y;
        acc[2] += a_ * xv.z;
        acc[3] += a_ * xv.w;
    }
    float* o = r_part + ((size_t)tc * BB + b) * DD + d0;
    *(float4*)o = *(float4*)&acc;
}

// ---------------- K5: out = relu(r @ Wp + lsWx), fused r-reduce + split-K (R5 form) ----
__global__ void final_out(const float* __restrict__ r_part, const float* __restrict__ Wp,
                          const float* __restrict__ lsWx, float* __restrict__ out) {
    __shared__ float rs[DD];
    __shared__ float red[4][64];
    int b = blockIdx.y;
    int e0 = blockIdx.x * 64;
    int tid = threadIdx.x;
    for (int d = tid; d < DD; d += 256) {
        float v = 0.f;
        #pragma unroll
        for (int p = 0; p < 16; p++) v += r_part[((size_t)p * BB + b) * DD + d];
        rs[d] = v;
    }
    __syncthreads();
    int e = tid & 63, dg = tid >> 6;
    int d0 = dg * 256;
    const float* Mp = Wp + (size_t)d0 * DIMQ + e0 + e;
    float acc = 0.f;
    #pragma unroll 8
    for (int d = 0; d < 256; d++) acc += rs[d0 + d] * Mp[(size_t)d * DIMQ];
    red[dg][e] = acc;
    __syncthreads();
    if (dg == 0) {
        float v = red[0][e] + red[1][e] + red[2][e] + red[3][e]
                + lsWx[b * DIMQ + e0 + e];
        out[b * DIMQ + e0 + e] = fmaxf(v, 0.f);
    }
}

extern "C" void kernel_launch(void* const* d_in, const int* in_sizes, int n_in,
                              void* d_out, int out_size, void* d_ws, size_t ws_size,
                              hipStream_t stream) {
    const float* x    = (const float*)d_in[0];  // (B,T,D)
    const float* last = (const float*)d_in[1];  // (B,D)
    const float* Wy   = (const float*)d_in[2];  // (D,DIM)
    const float* Wh   = (const float*)d_in[3];  // (D,DIM)
    const float* w    = (const float*)d_in[4];  // (DIM,1)
    const float* Wp   = (const float*)d_in[5];  // (D,DIM)
    const float* Wx   = (const float*)d_in[6];  // (D,DIM)
    float* out = (float*)d_out;

    // workspace layout (Xb slot retired; offsets kept stable)
    char* ws = (char*)d_ws;
    unsigned short* WyT  = (unsigned short*)(ws + 134217728);      // 2 MiB
    float* hproj         = (float*)(ws + 136314880);               // 128 KiB
    float* lsWx          = (float*)(ws + 136445952);               // 128 KiB
    float* partials      = (float*)(ws + 136577024);               // 1 MiB (4 x 65536)
    float* alpha         = (float*)(ws + 137625600);               // 256 KiB
    float* r_part        = (float*)(ws + 137887744);               // 2 MiB (16 x 32 x 1024)

    transpose_cast<<<dim3(32, 32), 256, 0, stream>>>(Wy, WyT);
    vecmat2<<<dim3(DIMQ/64, BB, 2), 256, 0, stream>>>(last, Wh, Wx, hproj, lsWx);
    gemm_scores<<<1024, 512, 0, stream>>>(x, WyT, hproj, w, partials);
    softmax_alpha<<<BB, 256, 0, stream>>>(partials, alpha);
    weighted_sum<<<dim3(TT/128, BB), 256, 0, stream>>>(x, alpha, r_part);
    final_out<<<dim3(DIMQ/64, BB), 256, 0, stream>>>(r_part, Wp, lsWx, out);
}

// Round 11
// 644.924 us; speedup vs baseline: 1.0739x; 1.0155x over previous
//
#include <hip/hip_runtime.h>
#include <hip/hip_bf16.h>
#include <stdint.h>

// Problem dims (fixed)
#define BB 32
#define TT 2048
#define DD 1024
#define DIMQ 1024
#define MTOT (BB*TT)   // 65536 rows of X flattened

typedef __attribute__((ext_vector_type(8))) __bf16 bf16x8;
typedef __attribute__((ext_vector_type(4))) float f32x4;

__device__ __forceinline__ unsigned short f2bf(float f) {
    unsigned int u = __float_as_uint(f);
    u += 0x7FFF + ((u >> 16) & 1);   // round-to-nearest-even
    return (unsigned short)(u >> 16);
}
__device__ __forceinline__ float bf2f(unsigned short s) {
    return __uint_as_float(((unsigned int)s) << 16);
}

__device__ __forceinline__ void load_lds16(const void* g, void* l) {
    __builtin_amdgcn_global_load_lds(
        (const __attribute__((address_space(1))) unsigned int*)g,
        (__attribute__((address_space(3))) unsigned int*)l,
        16, 0, 0);
}

// ---------------- K0: cast X f32 -> bf16, grid-stride (G11: ~2048 blocks, ILP) ----
// R5 version used 65536 one-shot blocks (1 float4/thread) and ran at ~3.7 TB/s
// (inferred ~100us). Grid-stride with 32 float4/thread targets the ~6 TB/s floor.
__global__ void cast_x(const float* __restrict__ x, unsigned short* __restrict__ xb) {
    const long N = (long)BB * TT * DD / 4;            // 16,777,216 float4s
    long stride = (long)gridDim.x * blockDim.x;
    long i = (long)blockIdx.x * blockDim.x + threadIdx.x;
    #pragma unroll 4
    for (; i < N; i += stride) {
        float4 a = ((const float4*)x)[i];
        ushort4 o;
        o.x = f2bf(a.x); o.y = f2bf(a.y); o.z = f2bf(a.z); o.w = f2bf(a.w);
        ((ushort4*)xb)[i] = o;
    }
}

// ---------------- K0b: Wy (D x DIM) f32 -> WyT (DIM x D) bf16 ----------------
__global__ void transpose_cast(const float* __restrict__ Wsrc, unsigned short* __restrict__ Wdst) {
    __shared__ float tile[32][33];
    int bx = blockIdx.x * 32;           // col (e) base
    int by = blockIdx.y * 32;           // row (d) base
    int tx = threadIdx.x & 31;
    int ty4 = (threadIdx.x >> 5) * 4;
    #pragma unroll
    for (int r = 0; r < 4; r++)
        tile[ty4 + r][tx] = Wsrc[(size_t)(by + ty4 + r) * DIMQ + bx + tx];
    __syncthreads();
    #pragma unroll
    for (int r = 0; r < 4; r++)
        Wdst[(size_t)(bx + ty4 + r) * DD + by + tx] = f2bf(tile[tx][ty4 + r]);
}

// ---------------- K1: fused dual vec-mat, split-K (R5 form — measurement-backed) ----
__global__ void vecmat2(const float* __restrict__ last,
                        const float* __restrict__ Wh, const float* __restrict__ Wx,
                        float* __restrict__ hproj, float* __restrict__ lsWx) {
    __shared__ float vs[DD];
    __shared__ float red[4][64];
    int b = blockIdx.y;
    int e0 = blockIdx.x * 64;
    const float* Mat = blockIdx.z ? Wx : Wh;
    float* outp = blockIdx.z ? lsWx : hproj;
    int tid = threadIdx.x;
    for (int d = tid; d < DD; d += 256) vs[d] = last[b * DD + d];
    __syncthreads();
    int e = tid & 63, dg = tid >> 6;
    int d0 = dg * 256;
    const float* Mp = Mat + (size_t)d0 * DIMQ + e0 + e;
    float acc = 0.f;
    #pragma unroll 8
    for (int d = 0; d < 256; d++) acc += vs[d0 + d] * Mp[(size_t)d * DIMQ];
    red[dg][e] = acc;
    __syncthreads();
    if (dg == 0)
        outp[b * DIMQ + e0 + e] = red[0][e] + red[1][e] + red[2][e] + red[3][e];
}

// ---------------- K2: fused GEMM + relu·w reduce -> partial scores ----------------
// R5 form (measured 193us, best): 256x256 tile, BK=64, 8 waves, 128 KiB dbuf LDS,
// 2-phase-per-K-tile counted-vmcnt schedule, bf16 Xb via global_load_lds DMA.
__global__ __launch_bounds__(512, 2)
void gemm_scores(const unsigned short* __restrict__ Xb,
                 const unsigned short* __restrict__ WyT,
                 const float* __restrict__ hproj,
                 const float* __restrict__ wvec,
                 float* __restrict__ partials) {
    // slot s: A at s*32768, B at s*32768+16384 (ushort idx); frag-ordered, 0 conflicts
    __shared__ unsigned short lds[65536];
    __shared__ float lp[256];

    int tid = threadIdx.x;
    int lane = tid & 63;
    int wave = tid >> 6;
    int wr = wave >> 2;          // 0..1  (M half: rows wr*128..+127)
    int wc = wave & 3;           // 0..3  (N quarter: cols wc*64..+63)

    // --- XCD-grouping swizzle: put the 4 ntile-siblings (same X-panel) on one XCD ---
    int bidx = blockIdx.x;
    int rr = bidx & 255, rnd = bidx >> 8;       // 4 rounds of 256 blocks
    int xcd = rr & 7, slot = rr >> 3;           // hw dispatch round-robins XCDs
    int ntile = slot & 3;
    int mtile = rnd * 64 + xcd * 8 + (slot >> 2);

    if (tid < 256) lp[tid] = 0.f;

    // staging: wave w stages chunk groups (sub=w>>1, ks=w&1) and (sub+4, ks)
    int ssub = wave >> 1, sks = wave & 1;
    const unsigned short* aG = Xb  + (size_t)(mtile * 256 + ssub * 16 + (lane & 15)) * DD + sks * 32 + (lane >> 4) * 8;
    const unsigned short* bG = WyT + (size_t)(ntile * 256 + ssub * 16 + (lane & 15)) * DD + sks * 32 + (lane >> 4) * 8;
    unsigned short* ldsAst = &lds[(ssub * 128 + sks * 64 + lane) * 8];
    unsigned short* ldsBst = ldsAst + 16384;

    // read bases (ushort units)
    const unsigned short* aRd = &lds[wr * 8192 + lane * 8];
    const unsigned short* bRd = &lds[16384 + (wc >> 1) * 8192 + (wc & 1) * 4096 + lane * 8];

#define STAGE_A(S_, H_, T_) { \
    const unsigned short* g_ = aG + (size_t)(H_) * 131072 + (T_) * 64; \
    load_lds16(g_,         ldsAst + (S_) * 32768 + (H_) * 8192);       \
    load_lds16(g_ + 65536, ldsAst + (S_) * 32768 + (H_) * 8192 + 4096); }
#define STAGE_B(S_, H_, T_) { \
    const unsigned short* g_ = bG + (size_t)(H_) * 131072 + (T_) * 64; \
    load_lds16(g_,         ldsBst + (S_) * 32768 + (H_) * 8192);       \
    load_lds16(g_ + 65536, ldsBst + (S_) * 32768 + (H_) * 8192 + 4096); }
#define STAGE_TILE(S_, T_) { STAGE_A(S_, 0, T_); STAGE_A(S_, 1, T_); \
                             STAGE_B(S_, 0, T_); STAGE_B(S_, 1, T_); }

    f32x4 acc[8][4] = {};
    bf16x8 af[4][2], bfr[4][2];

#define LDA(S_, MH) { \
    _Pragma("unroll") for (int i_ = 0; i_ < 4; i_++) \
    _Pragma("unroll") for (int k_ = 0; k_ < 2; k_++) \
        af[i_][k_] = *reinterpret_cast<const bf16x8*>(aRd + (S_) * 32768 + ((MH) * 4 + i_) * 1024 + k_ * 512); }
#define LDB(S_, NH) { \
    _Pragma("unroll") for (int j_ = 0; j_ < 2; j_++) \
    _Pragma("unroll") for (int k_ = 0; k_ < 2; k_++) \
        bfr[(NH) * 2 + j_][k_] = *reinterpret_cast<const bf16x8*>(bRd + (S_) * 32768 + ((NH) * 2 + j_) * 1024 + k_ * 512); }
#define MFMA_Q(MH, NH) { \
    _Pragma("unroll") for (int k_ = 0; k_ < 2; k_++) \
    _Pragma("unroll") for (int i_ = 0; i_ < 4; i_++) \
    _Pragma("unroll") for (int j_ = 0; j_ < 2; j_++) \
        acc[(MH) * 4 + i_][(NH) * 2 + j_] = __builtin_amdgcn_mfma_f32_16x16x32_bf16( \
            af[i_][k_], bfr[(NH) * 2 + j_][k_], acc[(MH) * 4 + i_][(NH) * 2 + j_], 0, 0, 0); }

#define BAR() __builtin_amdgcn_s_barrier()
#define LGKM0() asm volatile("s_waitcnt lgkmcnt(0)" ::: "memory")
#define VMW8() asm volatile("s_waitcnt vmcnt(8)" ::: "memory")
#define PRIO1() __builtin_amdgcn_s_setprio(1)
#define PRIO0() __builtin_amdgcn_s_setprio(0)

    // prologue: stage tile0 -> slot0, tile1 -> slot1 (16 loads outstanding)
    STAGE_TILE(0, 0);
    STAGE_TILE(1, 1);

    #pragma unroll 2
    for (int t = 0; t < 16; ++t) {
        int s = t & 1;
        int tp = (t + 2 > 15) ? 15 : (t + 2);   // tail re-stage (L2-hot, never read)

        VMW8();                 // tile t's 8 loads landed (newest 8 = tile t+1's)
        BAR();                  // slot s valid for every wave

        LDB(s, 0); LDB(s, 1);   // 8 ds_read_b128: all B frags
        LDA(s, 0);              // 8 ds_read_b128: A frags, M-half 0
        PRIO1(); MFMA_Q(0, 0); MFMA_Q(0, 1); PRIO0();   // 32 MFMA (compiler lgkm-waits)

        LDA(s, 1);              // 8 ds_read_b128: A frags, M-half 1
        LGKM0();                // my reads complete -> my regs hold slot s data
        BAR();                  // ALL waves done reading slot s -> slot dead

        STAGE_TILE(s, tp);      // 8 DMA into slot s; flight overlaps MFMA below
        PRIO1(); MFMA_Q(1, 0); MFMA_Q(1, 1); PRIO0();   // 32 MFMA
    }

    __syncthreads();   // drains trailing prefetches; epilogue uses lp only

    // Epilogue: partial score = sum_n relu(acc + hproj[b,n]) * w[n]
    int bIdx = mtile >> 3;                    // 8 mtiles per batch row-block
    int q = lane >> 4, l15 = lane & 15;

    float hpv[4], wvv[4];
    #pragma unroll
    for (int nf = 0; nf < 4; nf++) {
        int n = ntile * 256 + wc * 64 + nf * 16 + l15;
        hpv[nf] = hproj[bIdx * DIMQ + n];
        wvv[nf] = wvec[n];
    }

    #pragma unroll
    for (int m = 0; m < 8; m++) {
        f32x4 s = {0.f, 0.f, 0.f, 0.f};
        #pragma unroll
        for (int nf = 0; nf < 4; nf++) {
            #pragma unroll
            for (int r = 0; r < 4; r++) {
                float v = acc[m][nf][r] + hpv[nf];
                v = v > 0.f ? v : 0.f;
                s[r] += v * wvv[nf];
            }
        }
        #pragma unroll
        for (int off = 1; off < 16; off <<= 1) {
            s[0] += __shfl_xor(s[0], off);
            s[1] += __shfl_xor(s[1], off);
            s[2] += __shfl_xor(s[2], off);
            s[3] += __shfl_xor(s[3], off);
        }
        if (l15 == 0) {
            int mrow = wr * 128 + m * 16 + q * 4;
            atomicAdd(&lp[mrow + 0], s[0]);
            atomicAdd(&lp[mrow + 1], s[1]);
            atomicAdd(&lp[mrow + 2], s[2]);
            atomicAdd(&lp[mrow + 3], s[3]);
        }
    }
    __syncthreads();
    if (tid < 256)
        partials[(size_t)ntile * MTOT + mtile * 256 + tid] = lp[tid];

#undef STAGE_A
#undef STAGE_B
#undef STAGE_TILE
#undef LDA
#undef LDB
#undef MFMA_Q
#undef BAR
#undef LGKM0
#undef VMW8
#undef PRIO1
#undef PRIO0
}

// ---------------- K3: fused partial-sum + softmax over T (R5 form) ----------------
__global__ void softmax_alpha(const float* __restrict__ partials, float* __restrict__ alpha) {
    __shared__ float wred[4];
    __shared__ float wsum[4];
    int b = blockIdx.x;
    int tid = threadIdx.x;
    float s[8];
    float mx = -1e30f;
    #pragma unroll
    for (int c = 0; c < 8; c++) {
        int t = b * TT + tid + c * 256;
        float v = 0.f;
        #pragma unroll
        for (int p = 0; p < 4; p++) v += partials[(size_t)p * MTOT + t];
        s[c] = v;
        mx = fmaxf(mx, v);
    }
    for (int off = 32; off; off >>= 1) mx = fmaxf(mx, __shfl_xor(mx, off));
    if ((tid & 63) == 0) wred[tid >> 6] = mx;
    __syncthreads();
    mx = fmaxf(fmaxf(wred[0], wred[1]), fmaxf(wred[2], wred[3]));
    float sum = 0.f;
    #pragma unroll
    for (int c = 0; c < 8; c++) { s[c] = expf(s[c] - mx); sum += s[c]; }
    for (int off = 32; off; off >>= 1) sum += __shfl_xor(sum, off);
    if ((tid & 63) == 0) wsum[tid >> 6] = sum;
    __syncthreads();
    sum = wsum[0] + wsum[1] + wsum[2] + wsum[3];
    float inv = 1.f / sum;
    #pragma unroll
    for (int c = 0; c < 8; c++) alpha[b * TT + tid + c * 256] = s[c] * inv;
}

// ---------------- K4: r_part[tc][b][d] = sum_{t in 128-chunk} alpha * X ----------------
__global__ void weighted_sum(const unsigned short* __restrict__ Xb,
                             const float* __restrict__ alpha,
                             float* __restrict__ r_part) {
    __shared__ float al[128];
    int tc = blockIdx.x, b = blockIdx.y, tid = threadIdx.x;
    if (tid < 128) al[tid] = alpha[b * TT + tc * 128 + tid];
    __syncthreads();
    int d0 = tid * 4;
    const unsigned short* base = Xb + ((size_t)(b * TT + tc * 128)) * DD + d0;
    f32x4 acc = {0.f, 0.f, 0.f, 0.f};
    #pragma unroll 2
    for (int t = 0; t < 128; t++) {
        ushort4 xv = *(const ushort4*)(base + (size_t)t * DD);
        float a_ = al[t];
        acc[0] += a_ * bf2f(xv.x);
        acc[1] += a_ * bf2f(xv.y);
        acc[2] += a_ * bf2f(xv.z);
        acc[3] += a_ * bf2f(xv.w);
    }
    float* o = r_part + ((size_t)tc * BB + b) * DD + d0;
    *(float4*)o = *(float4*)&acc;
}

// ---------------- K5: out = relu(r @ Wp + lsWx), fused r-reduce + split-K (R5 form) ----
__global__ void final_out(const float* __restrict__ r_part, const float* __restrict__ Wp,
                          const float* __restrict__ lsWx, float* __restrict__ out) {
    __shared__ float rs[DD];
    __shared__ float red[4][64];
    int b = blockIdx.y;
    int e0 = blockIdx.x * 64;
    int tid = threadIdx.x;
    for (int d = tid; d < DD; d += 256) {
        float v = 0.f;
        #pragma unroll
        for (int p = 0; p < 16; p++) v += r_part[((size_t)p * BB + b) * DD + d];
        rs[d] = v;
    }
    __syncthreads();
    int e = tid & 63, dg = tid >> 6;
    int d0 = dg * 256;
    const float* Mp = Wp + (size_t)d0 * DIMQ + e0 + e;
    float acc = 0.f;
    #pragma unroll 8
    for (int d = 0; d < 256; d++) acc += rs[d0 + d] * Mp[(size_t)d * DIMQ];
    red[dg][e] = acc;
    __syncthreads();
    if (dg == 0) {
        float v = red[0][e] + red[1][e] + red[2][e] + red[3][e]
                + lsWx[b * DIMQ + e0 + e];
        out[b * DIMQ + e0 + e] = fmaxf(v, 0.f);
    }
}

extern "C" void kernel_launch(void* const* d_in, const int* in_sizes, int n_in,
                              void* d_out, int out_size, void* d_ws, size_t ws_size,
                              hipStream_t stream) {
    const float* x    = (const float*)d_in[0];  // (B,T,D)
    const float* last = (const float*)d_in[1];  // (B,D)
    const float* Wy   = (const float*)d_in[2];  // (D,DIM)
    const float* Wh   = (const float*)d_in[3];  // (D,DIM)
    const float* w    = (const float*)d_in[4];  // (DIM,1)
    const float* Wp   = (const float*)d_in[5];  // (D,DIM)
    const float* Wx   = (const float*)d_in[6];  // (D,DIM)
    float* out = (float*)d_out;

    // workspace layout (~134 MiB)
    char* ws = (char*)d_ws;
    unsigned short* Xb   = (unsigned short*)(ws);                  // 128 MiB
    unsigned short* WyT  = (unsigned short*)(ws + 134217728);      // 2 MiB
    float* hproj         = (float*)(ws + 136314880);               // 128 KiB
    float* lsWx          = (float*)(ws + 136445952);               // 128 KiB
    float* partials      = (float*)(ws + 136577024);               // 1 MiB (4 x 65536)
    float* alpha         = (float*)(ws + 137625600);               // 256 KiB
    float* r_part        = (float*)(ws + 137887744);               // 2 MiB (16 x 32 x 1024)

    cast_x<<<2048, 256, 0, stream>>>(x, Xb);
    transpose_cast<<<dim3(32, 32), 256, 0, stream>>>(Wy, WyT);
    vecmat2<<<dim3(DIMQ/64, BB, 2), 256, 0, stream>>>(last, Wh, Wx, hproj, lsWx);
    gemm_scores<<<1024, 512, 0, stream>>>(Xb, WyT, hproj, w, partials);
    softmax_alpha<<<BB, 256, 0, stream>>>(partials, alpha);
    weighted_sum<<<dim3(TT/128, BB), 256, 0, stream>>>(Xb, alpha, r_part);
    final_out<<<dim3(DIMQ/64, BB), 256, 0, stream>>>(r_part, Wp, lsWx, out);
}

// Round 13
// 630.426 us; speedup vs baseline: 1.0986x; 1.0230x over previous
//
#include <hip/hip_runtime.h>
#include <hip/hip_bf16.h>
#include <stdint.h>

// Problem dims (fixed)
#define BB 32
#define TT 2048
#define DD 1024
#define DIMQ 1024
#define MTOT (BB*TT)   // 65536 rows of X flattened

typedef __attribute__((ext_vector_type(8))) __bf16 bf16x8;
typedef __attribute__((ext_vector_type(4))) float f32x4;

__device__ __forceinline__ unsigned short f2bf(float f) {
    unsigned int u = __float_as_uint(f);
    u += 0x7FFF + ((u >> 16) & 1);   // round-to-nearest-even
    return (unsigned short)(u >> 16);
}
__device__ __forceinline__ float bf2f(unsigned short s) {
    return __uint_as_float(((unsigned int)s) << 16);
}
__device__ __forceinline__ unsigned int pk2bf(float lo, float hi) {
    return (unsigned int)f2bf(lo) | ((unsigned int)f2bf(hi) << 16);
}

__device__ __forceinline__ void load_lds16(const void* g, void* l) {
    __builtin_amdgcn_global_load_lds(
        (const __attribute__((address_space(1))) unsigned int*)g,
        (__attribute__((address_space(3))) unsigned int*)l,
        16, 0, 0);
}

// ---------------- K0: cast X f32 -> bf16, 8 elems/thread, 16B/lane stores ----------
// R5's version stored ushort4 (8B/lane — half the coalescing sweet spot) and ran
// at ~3.7 TB/s (~103us inferred). R11's grid-stride variant was worse (+23us).
// This keeps the one-shot grid shape but widens: 2x float4 loads -> 1x uint4 store.
__global__ void cast_x(const float* __restrict__ x, unsigned short* __restrict__ xb) {
    long i = ((long)blockIdx.x * blockDim.x + threadIdx.x) * 8;
    float4 a = *(const float4*)(x + i);
    float4 b = *(const float4*)(x + i + 4);
    uint4 pk;
    pk.x = pk2bf(a.x, a.y);
    pk.y = pk2bf(a.z, a.w);
    pk.z = pk2bf(b.x, b.y);
    pk.w = pk2bf(b.z, b.w);
    *(uint4*)(xb + i) = pk;
}

// ---------------- K0b: Wy (D x DIM) f32 -> WyT (DIM x D) bf16 ----------------
__global__ void transpose_cast(const float* __restrict__ Wsrc, unsigned short* __restrict__ Wdst) {
    __shared__ float tile[32][33];
    int bx = blockIdx.x * 32;           // col (e) base
    int by = blockIdx.y * 32;           // row (d) base
    int tx = threadIdx.x & 31;
    int ty4 = (threadIdx.x >> 5) * 4;
    #pragma unroll
    for (int r = 0; r < 4; r++)
        tile[ty4 + r][tx] = Wsrc[(size_t)(by + ty4 + r) * DIMQ + bx + tx];
    __syncthreads();
    #pragma unroll
    for (int r = 0; r < 4; r++)
        Wdst[(size_t)(bx + ty4 + r) * DD + by + tx] = f2bf(tile[tx][ty4 + r]);
}

// ---------------- K1: fused dual vec-mat, split-K (R5 form — measurement-backed) ----
__global__ void vecmat2(const float* __restrict__ last,
                        const float* __restrict__ Wh, const float* __restrict__ Wx,
                        float* __restrict__ hproj, float* __restrict__ lsWx) {
    __shared__ float vs[DD];
    __shared__ float red[4][64];
    int b = blockIdx.y;
    int e0 = blockIdx.x * 64;
    const float* Mat = blockIdx.z ? Wx : Wh;
    float* outp = blockIdx.z ? lsWx : hproj;
    int tid = threadIdx.x;
    for (int d = tid; d < DD; d += 256) vs[d] = last[b * DD + d];
    __syncthreads();
    int e = tid & 63, dg = tid >> 6;
    int d0 = dg * 256;
    const float* Mp = Mat + (size_t)d0 * DIMQ + e0 + e;
    float acc = 0.f;
    #pragma unroll 8
    for (int d = 0; d < 256; d++) acc += vs[d0 + d] * Mp[(size_t)d * DIMQ];
    red[dg][e] = acc;
    __syncthreads();
    if (dg == 0)
        outp[b * DIMQ + e0 + e] = red[0][e] + red[1][e] + red[2][e] + red[3][e];
}

// ---------------- K2: fused GEMM + relu·w reduce -> partial scores ----------------
// R5 form (measured 193us, best): 256x256 tile, BK=64, 8 waves, 128 KiB dbuf LDS,
// 2-phase-per-K-tile counted-vmcnt schedule, bf16 Xb via global_load_lds DMA.
__global__ __launch_bounds__(512, 2)
void gemm_scores(const unsigned short* __restrict__ Xb,
                 const unsigned short* __restrict__ WyT,
                 const float* __restrict__ hproj,
                 const float* __restrict__ wvec,
                 float* __restrict__ partials) {
    // slot s: A at s*32768, B at s*32768+16384 (ushort idx); frag-ordered, 0 conflicts
    __shared__ unsigned short lds[65536];
    __shared__ float lp[256];

    int tid = threadIdx.x;
    int lane = tid & 63;
    int wave = tid >> 6;
    int wr = wave >> 2;          // 0..1  (M half: rows wr*128..+127)
    int wc = wave & 3;           // 0..3  (N quarter: cols wc*64..+63)

    // --- XCD-grouping swizzle: put the 4 ntile-siblings (same X-panel) on one XCD ---
    int bidx = blockIdx.x;
    int rr = bidx & 255, rnd = bidx >> 8;       // 4 rounds of 256 blocks
    int xcd = rr & 7, slot = rr >> 3;           // hw dispatch round-robins XCDs
    int ntile = slot & 3;
    int mtile = rnd * 64 + xcd * 8 + (slot >> 2);

    if (tid < 256) lp[tid] = 0.f;

    // staging: wave w stages chunk groups (sub=w>>1, ks=w&1) and (sub+4, ks)
    int ssub = wave >> 1, sks = wave & 1;
    const unsigned short* aG = Xb  + (size_t)(mtile * 256 + ssub * 16 + (lane & 15)) * DD + sks * 32 + (lane >> 4) * 8;
    const unsigned short* bG = WyT + (size_t)(ntile * 256 + ssub * 16 + (lane & 15)) * DD + sks * 32 + (lane >> 4) * 8;
    unsigned short* ldsAst = &lds[(ssub * 128 + sks * 64 + lane) * 8];
    unsigned short* ldsBst = ldsAst + 16384;

    // read bases (ushort units)
    const unsigned short* aRd = &lds[wr * 8192 + lane * 8];
    const unsigned short* bRd = &lds[16384 + (wc >> 1) * 8192 + (wc & 1) * 4096 + lane * 8];

#define STAGE_A(S_, H_, T_) { \
    const unsigned short* g_ = aG + (size_t)(H_) * 131072 + (T_) * 64; \
    load_lds16(g_,         ldsAst + (S_) * 32768 + (H_) * 8192);       \
    load_lds16(g_ + 65536, ldsAst + (S_) * 32768 + (H_) * 8192 + 4096); }
#define STAGE_B(S_, H_, T_) { \
    const unsigned short* g_ = bG + (size_t)(H_) * 131072 + (T_) * 64; \
    load_lds16(g_,         ldsBst + (S_) * 32768 + (H_) * 8192);       \
    load_lds16(g_ + 65536, ldsBst + (S_) * 32768 + (H_) * 8192 + 4096); }
#define STAGE_TILE(S_, T_) { STAGE_A(S_, 0, T_); STAGE_A(S_, 1, T_); \
                             STAGE_B(S_, 0, T_); STAGE_B(S_, 1, T_); }

    f32x4 acc[8][4] = {};
    bf16x8 af[4][2], bfr[4][2];

#define LDA(S_, MH) { \
    _Pragma("unroll") for (int i_ = 0; i_ < 4; i_++) \
    _Pragma("unroll") for (int k_ = 0; k_ < 2; k_++) \
        af[i_][k_] = *reinterpret_cast<const bf16x8*>(aRd + (S_) * 32768 + ((MH) * 4 + i_) * 1024 + k_ * 512); }
#define LDB(S_, NH) { \
    _Pragma("unroll") for (int j_ = 0; j_ < 2; j_++) \
    _Pragma("unroll") for (int k_ = 0; k_ < 2; k_++) \
        bfr[(NH) * 2 + j_][k_] = *reinterpret_cast<const bf16x8*>(bRd + (S_) * 32768 + ((NH) * 2 + j_) * 1024 + k_ * 512); }
#define MFMA_Q(MH, NH) { \
    _Pragma("unroll") for (int k_ = 0; k_ < 2; k_++) \
    _Pragma("unroll") for (int i_ = 0; i_ < 4; i_++) \
    _Pragma("unroll") for (int j_ = 0; j_ < 2; j_++) \
        acc[(MH) * 4 + i_][(NH) * 2 + j_] = __builtin_amdgcn_mfma_f32_16x16x32_bf16( \
            af[i_][k_], bfr[(NH) * 2 + j_][k_], acc[(MH) * 4 + i_][(NH) * 2 + j_], 0, 0, 0); }

#define BAR() __builtin_amdgcn_s_barrier()
#define LGKM0() asm volatile("s_waitcnt lgkmcnt(0)" ::: "memory")
#define VMW8() asm volatile("s_waitcnt vmcnt(8)" ::: "memory")
#define PRIO1() __builtin_amdgcn_s_setprio(1)
#define PRIO0() __builtin_amdgcn_s_setprio(0)

    // prologue: stage tile0 -> slot0, tile1 -> slot1 (16 loads outstanding)
    STAGE_TILE(0, 0);
    STAGE_TILE(1, 1);

    #pragma unroll 2
    for (int t = 0; t < 16; ++t) {
        int s = t & 1;
        int tp = (t + 2 > 15) ? 15 : (t + 2);   // tail re-stage (L2-hot, never read)

        VMW8();                 // tile t's 8 loads landed (newest 8 = tile t+1's)
        BAR();                  // slot s valid for every wave

        LDB(s, 0); LDB(s, 1);   // 8 ds_read_b128: all B frags
        LDA(s, 0);              // 8 ds_read_b128: A frags, M-half 0
        PRIO1(); MFMA_Q(0, 0); MFMA_Q(0, 1); PRIO0();   // 32 MFMA (compiler lgkm-waits)

        LDA(s, 1);              // 8 ds_read_b128: A frags, M-half 1
        LGKM0();                // my reads complete -> my regs hold slot s data
        BAR();                  // ALL waves done reading slot s -> slot dead

        STAGE_TILE(s, tp);      // 8 DMA into slot s; flight overlaps MFMA below
        PRIO1(); MFMA_Q(1, 0); MFMA_Q(1, 1); PRIO0();   // 32 MFMA
    }

    __syncthreads();   // drains trailing prefetches; epilogue uses lp only

    // Epilogue: partial score = sum_n relu(acc + hproj[b,n]) * w[n]
    int bIdx = mtile >> 3;                    // 8 mtiles per batch row-block
    int q = lane >> 4, l15 = lane & 15;

    float hpv[4], wvv[4];
    #pragma unroll
    for (int nf = 0; nf < 4; nf++) {
        int n = ntile * 256 + wc * 64 + nf * 16 + l15;
        hpv[nf] = hproj[bIdx * DIMQ + n];
        wvv[nf] = wvec[n];
    }

    #pragma unroll
    for (int m = 0; m < 8; m++) {
        f32x4 s = {0.f, 0.f, 0.f, 0.f};
        #pragma unroll
        for (int nf = 0; nf < 4; nf++) {
            #pragma unroll
            for (int r = 0; r < 4; r++) {
                float v = acc[m][nf][r] + hpv[nf];
                v = v > 0.f ? v : 0.f;
                s[r] += v * wvv[nf];
            }
        }
        #pragma unroll
        for (int off = 1; off < 16; off <<= 1) {
            s[0] += __shfl_xor(s[0], off);
            s[1] += __shfl_xor(s[1], off);
            s[2] += __shfl_xor(s[2], off);
            s[3] += __shfl_xor(s[3], off);
        }
        if (l15 == 0) {
            int mrow = wr * 128 + m * 16 + q * 4;
            atomicAdd(&lp[mrow + 0], s[0]);
            atomicAdd(&lp[mrow + 1], s[1]);
            atomicAdd(&lp[mrow + 2], s[2]);
            atomicAdd(&lp[mrow + 3], s[3]);
        }
    }
    __syncthreads();
    if (tid < 256)
        partials[(size_t)ntile * MTOT + mtile * 256 + tid] = lp[tid];

#undef STAGE_A
#undef STAGE_B
#undef STAGE_TILE
#undef LDA
#undef LDB
#undef MFMA_Q
#undef BAR
#undef LGKM0
#undef VMW8
#undef PRIO1
#undef PRIO0
}

// ---------------- K3: fused partial-sum + softmax over T (R5 form) ----------------
__global__ void softmax_alpha(const float* __restrict__ partials, float* __restrict__ alpha) {
    __shared__ float wred[4];
    __shared__ float wsum[4];
    int b = blockIdx.x;
    int tid = threadIdx.x;
    float s[8];
    float mx = -1e30f;
    #pragma unroll
    for (int c = 0; c < 8; c++) {
        int t = b * TT + tid + c * 256;
        float v = 0.f;
        #pragma unroll
        for (int p = 0; p < 4; p++) v += partials[(size_t)p * MTOT + t];
        s[c] = v;
        mx = fmaxf(mx, v);
    }
    for (int off = 32; off; off >>= 1) mx = fmaxf(mx, __shfl_xor(mx, off));
    if ((tid & 63) == 0) wred[tid >> 6] = mx;
    __syncthreads();
    mx = fmaxf(fmaxf(wred[0], wred[1]), fmaxf(wred[2], wred[3]));
    float sum = 0.f;
    #pragma unroll
    for (int c = 0; c < 8; c++) { s[c] = expf(s[c] - mx); sum += s[c]; }
    for (int off = 32; off; off >>= 1) sum += __shfl_xor(sum, off);
    if ((tid & 63) == 0) wsum[tid >> 6] = sum;
    __syncthreads();
    sum = wsum[0] + wsum[1] + wsum[2] + wsum[3];
    float inv = 1.f / sum;
    #pragma unroll
    for (int c = 0; c < 8; c++) alpha[b * TT + tid + c * 256] = s[c] * inv;
}

// ---------------- K4: r_part[tc][b][d] = sum_{t in 128-chunk} alpha * X ----------------
__global__ void weighted_sum(const unsigned short* __restrict__ Xb,
                             const float* __restrict__ alpha,
                             float* __restrict__ r_part) {
    __shared__ float al[128];
    int tc = blockIdx.x, b = blockIdx.y, tid = threadIdx.x;
    if (tid < 128) al[tid] = alpha[b * TT + tc * 128 + tid];
    __syncthreads();
    int d0 = tid * 4;
    const unsigned short* base = Xb + ((size_t)(b * TT + tc * 128)) * DD + d0;
    f32x4 acc = {0.f, 0.f, 0.f, 0.f};
    #pragma unroll 2
    for (int t = 0; t < 128; t++) {
        ushort4 xv = *(const ushort4*)(base + (size_t)t * DD);
        float a_ = al[t];
        acc[0] += a_ * bf2f(xv.x);
        acc[1] += a_ * bf2f(xv.y);
        acc[2] += a_ * bf2f(xv.z);
        acc[3] += a_ * bf2f(xv.w);
    }
    float* o = r_part + ((size_t)tc * BB + b) * DD + d0;
    *(float4*)o = *(float4*)&acc;
}

// ---------------- K5: out = relu(r @ Wp + lsWx), fused r-reduce + split-K (R5 form) ----
__global__ void final_out(const float* __restrict__ r_part, const float* __restrict__ Wp,
                          const float* __restrict__ lsWx, float* __restrict__ out) {
    __shared__ float rs[DD];
    __shared__ float red[4][64];
    int b = blockIdx.y;
    int e0 = blockIdx.x * 64;
    int tid = threadIdx.x;
    for (int d = tid; d < DD; d += 256) {
        float v = 0.f;
        #pragma unroll
        for (int p = 0; p < 16; p++) v += r_part[((size_t)p * BB + b) * DD + d];
        rs[d] = v;
    }
    __syncthreads();
    int e = tid & 63, dg = tid >> 6;
    int d0 = dg * 256;
    const float* Mp = Wp + (size_t)d0 * DIMQ + e0 + e;
    float acc = 0.f;
    #pragma unroll 8
    for (int d = 0; d < 256; d++) acc += rs[d0 + d] * Mp[(size_t)d * DIMQ];
    red[dg][e] = acc;
    __syncthreads();
    if (dg == 0) {
        float v = red[0][e] + red[1][e] + red[2][e] + red[3][e]
                + lsWx[b * DIMQ + e0 + e];
        out[b * DIMQ + e0 + e] = fmaxf(v, 0.f);
    }
}

extern "C" void kernel_launch(void* const* d_in, const int* in_sizes, int n_in,
                              void* d_out, int out_size, void* d_ws, size_t ws_size,
                              hipStream_t stream) {
    const float* x    = (const float*)d_in[0];  // (B,T,D)
    const float* last = (const float*)d_in[1];  // (B,D)
    const float* Wy   = (const float*)d_in[2];  // (D,DIM)
    const float* Wh   = (const float*)d_in[3];  // (D,DIM)
    const float* w    = (const float*)d_in[4];  // (DIM,1)
    const float* Wp   = (const float*)d_in[5];  // (D,DIM)
    const float* Wx   = (const float*)d_in[6];  // (D,DIM)
    float* out = (float*)d_out;

    // workspace layout (~134 MiB)
    char* ws = (char*)d_ws;
    unsigned short* Xb   = (unsigned short*)(ws);                  // 128 MiB
    unsigned short* WyT  = (unsigned short*)(ws + 134217728);      // 2 MiB
    float* hproj         = (float*)(ws + 136314880);               // 128 KiB
    float* lsWx          = (float*)(ws + 136445952);               // 128 KiB
    float* partials      = (float*)(ws + 136577024);               // 1 MiB (4 x 65536)
    float* alpha         = (float*)(ws + 137625600);               // 256 KiB
    float* r_part        = (float*)(ws + 137887744);               // 2 MiB (16 x 32 x 1024)

    cast_x<<<BB*TT*DD/8/256, 256, 0, stream>>>(x, Xb);
    transpose_cast<<<dim3(32, 32), 256, 0, stream>>>(Wy, WyT);
    vecmat2<<<dim3(DIMQ/64, BB, 2), 256, 0, stream>>>(last, Wh, Wx, hproj, lsWx);
    gemm_scores<<<1024, 512, 0, stream>>>(Xb, WyT, hproj, w, partials);
    softmax_alpha<<<BB, 256, 0, stream>>>(partials, alpha);
    weighted_sum<<<dim3(TT/128, BB), 256, 0, stream>>>(Xb, alpha, r_part);
    final_out<<<dim3(DIMQ/64, BB), 256, 0, stream>>>(r_part, Wp, lsWx, out);
}

// Round 14
// 602.368 us; speedup vs baseline: 1.1498x; 1.0466x over previous
//
#include <hip/hip_runtime.h>
#include <hip/hip_bf16.h>
#include <stdint.h>

// Problem dims (fixed)
#define BB 32
#define TT 2048
#define DD 1024
#define DIMQ 1024
#define MTOT (BB*TT)   // 65536 rows of X flattened

typedef __attribute__((ext_vector_type(8))) __bf16 bf16x8;
typedef __attribute__((ext_vector_type(4))) float f32x4;

__device__ __forceinline__ unsigned short f2bf(float f) {
    unsigned int u = __float_as_uint(f);
    u += 0x7FFF + ((u >> 16) & 1);   // round-to-nearest-even
    return (unsigned short)(u >> 16);
}
__device__ __forceinline__ float bf2f(unsigned short s) {
    return __uint_as_float(((unsigned int)s) << 16);
}

__device__ __forceinline__ void load_lds16(const void* g, void* l) {
    __builtin_amdgcn_global_load_lds(
        (const __attribute__((address_space(1))) unsigned int*)g,
        (__attribute__((address_space(3))) unsigned int*)l,
        16, 0, 0);
}

// ---------------- K0: fused prep — vecmat2 ∥ transpose_cast ∥ cast_x ----------------
// The three front kernels are data-independent but were serialized on one stream
// (~25-30us of small-kernel time hiding available inside cast_x's BW-bound window).
// One launch, block-range partitioned; each inner body is byte-identical to its
// measured-good standalone form (R5). vecmat2/transpose blocks first so they
// dispatch immediately alongside the cast wave.
__global__ void prep_fused(const float* __restrict__ x, unsigned short* __restrict__ xb,
                           const float* __restrict__ Wy, unsigned short* __restrict__ WyT,
                           const float* __restrict__ last,
                           const float* __restrict__ Wh, const float* __restrict__ Wx,
                           float* __restrict__ hproj, float* __restrict__ lsWx) {
    __shared__ float sm[1344];    // 5376 B union: vecmat2 (vs+red = 5 KB) / transpose (4.2 KB)
    int bid = blockIdx.x;
    int tid = threadIdx.x;

    if (bid >= 2048) {
        // ---- cast_x part (R5 naive form: 1 float4/thread, best-measured) ----
        long i = ((long)(bid - 2048) * 256 + tid) * 4;
        float4 a = *(const float4*)(x + i);
        ushort4 o;
        o.x = f2bf(a.x); o.y = f2bf(a.y); o.z = f2bf(a.z); o.w = f2bf(a.w);
        *(ushort4*)(xb + i) = o;
        return;
    }

    if (bid >= 1024) {
        // ---- transpose_cast part: Wy (D x DIM) f32 -> WyT (DIM x D) bf16 ----
        float (*tile)[33] = (float (*)[33])sm;   // [32][33] = 4224 B
        int t = bid - 1024;
        int bx = (t & 31) * 32;            // col (e) base
        int by = (t >> 5) * 32;            // row (d) base
        int tx = tid & 31;
        int ty4 = (tid >> 5) * 4;
        #pragma unroll
        for (int r = 0; r < 4; r++)
            tile[ty4 + r][tx] = Wy[(size_t)(by + ty4 + r) * DIMQ + bx + tx];
        __syncthreads();
        #pragma unroll
        for (int r = 0; r < 4; r++)
            WyT[(size_t)(bx + ty4 + r) * DD + by + tx] = f2bf(tile[tx][ty4 + r]);
        return;
    }

    // ---- vecmat2 part (R5 form): dual vec-mat, split-K ----
    float* vs = sm;                               // [1024]
    float (*red)[64] = (float (*)[64])(sm + 1024); // [4][64]
    int e0 = (bid & 15) * 64;
    int b  = (bid >> 4) & 31;
    int z  = bid >> 9;
    const float* Mat = z ? Wx : Wh;
    float* outp = z ? lsWx : hproj;
    for (int d = tid; d < DD; d += 256) vs[d] = last[b * DD + d];
    __syncthreads();
    int e = tid & 63, dg = tid >> 6;
    int d0 = dg * 256;
    const float* Mp = Mat + (size_t)d0 * DIMQ + e0 + e;
    float acc = 0.f;
    #pragma unroll 8
    for (int d = 0; d < 256; d++) acc += vs[d0 + d] * Mp[(size_t)d * DIMQ];
    red[dg][e] = acc;
    __syncthreads();
    if (dg == 0)
        outp[b * DIMQ + e0 + e] = red[0][e] + red[1][e] + red[2][e] + red[3][e];
}

// ---------------- K2: fused GEMM + relu·w reduce -> partial scores ----------------
// R5 form (measured 193us, best): 256x256 tile, BK=64, 8 waves, 128 KiB dbuf LDS,
// 2-phase-per-K-tile counted-vmcnt schedule, bf16 Xb via global_load_lds DMA.
__global__ __launch_bounds__(512, 2)
void gemm_scores(const unsigned short* __restrict__ Xb,
                 const unsigned short* __restrict__ WyT,
                 const float* __restrict__ hproj,
                 const float* __restrict__ wvec,
                 float* __restrict__ partials) {
    // slot s: A at s*32768, B at s*32768+16384 (ushort idx); frag-ordered, 0 conflicts
    __shared__ unsigned short lds[65536];
    __shared__ float lp[256];

    int tid = threadIdx.x;
    int lane = tid & 63;
    int wave = tid >> 6;
    int wr = wave >> 2;          // 0..1  (M half: rows wr*128..+127)
    int wc = wave & 3;           // 0..3  (N quarter: cols wc*64..+63)

    // --- XCD-grouping swizzle: put the 4 ntile-siblings (same X-panel) on one XCD ---
    int bidx = blockIdx.x;
    int rr = bidx & 255, rnd = bidx >> 8;       // 4 rounds of 256 blocks
    int xcd = rr & 7, slot = rr >> 3;           // hw dispatch round-robins XCDs
    int ntile = slot & 3;
    int mtile = rnd * 64 + xcd * 8 + (slot >> 2);

    if (tid < 256) lp[tid] = 0.f;

    // staging: wave w stages chunk groups (sub=w>>1, ks=w&1) and (sub+4, ks)
    int ssub = wave >> 1, sks = wave & 1;
    const unsigned short* aG = Xb  + (size_t)(mtile * 256 + ssub * 16 + (lane & 15)) * DD + sks * 32 + (lane >> 4) * 8;
    const unsigned short* bG = WyT + (size_t)(ntile * 256 + ssub * 16 + (lane & 15)) * DD + sks * 32 + (lane >> 4) * 8;
    unsigned short* ldsAst = &lds[(ssub * 128 + sks * 64 + lane) * 8];
    unsigned short* ldsBst = ldsAst + 16384;

    // read bases (ushort units)
    const unsigned short* aRd = &lds[wr * 8192 + lane * 8];
    const unsigned short* bRd = &lds[16384 + (wc >> 1) * 8192 + (wc & 1) * 4096 + lane * 8];

#define STAGE_A(S_, H_, T_) { \
    const unsigned short* g_ = aG + (size_t)(H_) * 131072 + (T_) * 64; \
    load_lds16(g_,         ldsAst + (S_) * 32768 + (H_) * 8192);       \
    load_lds16(g_ + 65536, ldsAst + (S_) * 32768 + (H_) * 8192 + 4096); }
#define STAGE_B(S_, H_, T_) { \
    const unsigned short* g_ = bG + (size_t)(H_) * 131072 + (T_) * 64; \
    load_lds16(g_,         ldsBst + (S_) * 32768 + (H_) * 8192);       \
    load_lds16(g_ + 65536, ldsBst + (S_) * 32768 + (H_) * 8192 + 4096); }
#define STAGE_TILE(S_, T_) { STAGE_A(S_, 0, T_); STAGE_A(S_, 1, T_); \
                             STAGE_B(S_, 0, T_); STAGE_B(S_, 1, T_); }

    f32x4 acc[8][4] = {};
    bf16x8 af[4][2], bfr[4][2];

#define LDA(S_, MH) { \
    _Pragma("unroll") for (int i_ = 0; i_ < 4; i_++) \
    _Pragma("unroll") for (int k_ = 0; k_ < 2; k_++) \
        af[i_][k_] = *reinterpret_cast<const bf16x8*>(aRd + (S_) * 32768 + ((MH) * 4 + i_) * 1024 + k_ * 512); }
#define LDB(S_, NH) { \
    _Pragma("unroll") for (int j_ = 0; j_ < 2; j_++) \
    _Pragma("unroll") for (int k_ = 0; k_ < 2; k_++) \
        bfr[(NH) * 2 + j_][k_] = *reinterpret_cast<const bf16x8*>(bRd + (S_) * 32768 + ((NH) * 2 + j_) * 1024 + k_ * 512); }
#define MFMA_Q(MH, NH) { \
    _Pragma("unroll") for (int k_ = 0; k_ < 2; k_++) \
    _Pragma("unroll") for (int i_ = 0; i_ < 4; i_++) \
    _Pragma("unroll") for (int j_ = 0; j_ < 2; j_++) \
        acc[(MH) * 4 + i_][(NH) * 2 + j_] = __builtin_amdgcn_mfma_f32_16x16x32_bf16( \
            af[i_][k_], bfr[(NH) * 2 + j_][k_], acc[(MH) * 4 + i_][(NH) * 2 + j_], 0, 0, 0); }

#define BAR() __builtin_amdgcn_s_barrier()
#define LGKM0() asm volatile("s_waitcnt lgkmcnt(0)" ::: "memory")
#define VMW8() asm volatile("s_waitcnt vmcnt(8)" ::: "memory")
#define PRIO1() __builtin_amdgcn_s_setprio(1)
#define PRIO0() __builtin_amdgcn_s_setprio(0)

    // prologue: stage tile0 -> slot0, tile1 -> slot1 (16 loads outstanding)
    STAGE_TILE(0, 0);
    STAGE_TILE(1, 1);

    #pragma unroll 2
    for (int t = 0; t < 16; ++t) {
        int s = t & 1;
        int tp = (t + 2 > 15) ? 15 : (t + 2);   // tail re-stage (L2-hot, never read)

        VMW8();                 // tile t's 8 loads landed (newest 8 = tile t+1's)
        BAR();                  // slot s valid for every wave

        LDB(s, 0); LDB(s, 1);   // 8 ds_read_b128: all B frags
        LDA(s, 0);              // 8 ds_read_b128: A frags, M-half 0
        PRIO1(); MFMA_Q(0, 0); MFMA_Q(0, 1); PRIO0();   // 32 MFMA (compiler lgkm-waits)

        LDA(s, 1);              // 8 ds_read_b128: A frags, M-half 1
        LGKM0();                // my reads complete -> my regs hold slot s data
        BAR();                  // ALL waves done reading slot s -> slot dead

        STAGE_TILE(s, tp);      // 8 DMA into slot s; flight overlaps MFMA below
        PRIO1(); MFMA_Q(1, 0); MFMA_Q(1, 1); PRIO0();   // 32 MFMA
    }

    __syncthreads();   // drains trailing prefetches; epilogue uses lp only

    // Epilogue: partial score = sum_n relu(acc + hproj[b,n]) * w[n]
    int bIdx = mtile >> 3;                    // 8 mtiles per batch row-block
    int q = lane >> 4, l15 = lane & 15;

    float hpv[4], wvv[4];
    #pragma unroll
    for (int nf = 0; nf < 4; nf++) {
        int n = ntile * 256 + wc * 64 + nf * 16 + l15;
        hpv[nf] = hproj[bIdx * DIMQ + n];
        wvv[nf] = wvec[n];
    }

    #pragma unroll
    for (int m = 0; m < 8; m++) {
        f32x4 s = {0.f, 0.f, 0.f, 0.f};
        #pragma unroll
        for (int nf = 0; nf < 4; nf++) {
            #pragma unroll
            for (int r = 0; r < 4; r++) {
                float v = acc[m][nf][r] + hpv[nf];
                v = v > 0.f ? v : 0.f;
                s[r] += v * wvv[nf];
            }
        }
        #pragma unroll
        for (int off = 1; off < 16; off <<= 1) {
            s[0] += __shfl_xor(s[0], off);
            s[1] += __shfl_xor(s[1], off);
            s[2] += __shfl_xor(s[2], off);
            s[3] += __shfl_xor(s[3], off);
        }
        if (l15 == 0) {
            int mrow = wr * 128 + m * 16 + q * 4;
            atomicAdd(&lp[mrow + 0], s[0]);
            atomicAdd(&lp[mrow + 1], s[1]);
            atomicAdd(&lp[mrow + 2], s[2]);
            atomicAdd(&lp[mrow + 3], s[3]);
        }
    }
    __syncthreads();
    if (tid < 256)
        partials[(size_t)ntile * MTOT + mtile * 256 + tid] = lp[tid];

#undef STAGE_A
#undef STAGE_B
#undef STAGE_TILE
#undef LDA
#undef LDB
#undef MFMA_Q
#undef BAR
#undef LGKM0
#undef VMW8
#undef PRIO1
#undef PRIO0
}

// ---------------- K3: fused partial-sum + softmax over T (R5 form) ----------------
__global__ void softmax_alpha(const float* __restrict__ partials, float* __restrict__ alpha) {
    __shared__ float wred[4];
    __shared__ float wsum[4];
    int b = blockIdx.x;
    int tid = threadIdx.x;
    float s[8];
    float mx = -1e30f;
    #pragma unroll
    for (int c = 0; c < 8; c++) {
        int t = b * TT + tid + c * 256;
        float v = 0.f;
        #pragma unroll
        for (int p = 0; p < 4; p++) v += partials[(size_t)p * MTOT + t];
        s[c] = v;
        mx = fmaxf(mx, v);
    }
    for (int off = 32; off; off >>= 1) mx = fmaxf(mx, __shfl_xor(mx, off));
    if ((tid & 63) == 0) wred[tid >> 6] = mx;
    __syncthreads();
    mx = fmaxf(fmaxf(wred[0], wred[1]), fmaxf(wred[2], wred[3]));
    float sum = 0.f;
    #pragma unroll
    for (int c = 0; c < 8; c++) { s[c] = expf(s[c] - mx); sum += s[c]; }
    for (int off = 32; off; off >>= 1) sum += __shfl_xor(sum, off);
    if ((tid & 63) == 0) wsum[tid >> 6] = sum;
    __syncthreads();
    sum = wsum[0] + wsum[1] + wsum[2] + wsum[3];
    float inv = 1.f / sum;
    #pragma unroll
    for (int c = 0; c < 8; c++) alpha[b * TT + tid + c * 256] = s[c] * inv;
}

// ---------------- K4: r_part[tc][b][d] = sum_{t in 128-chunk} alpha * X ----------------
__global__ void weighted_sum(const unsigned short* __restrict__ Xb,
                             const float* __restrict__ alpha,
                             float* __restrict__ r_part) {
    __shared__ float al[128];
    int tc = blockIdx.x, b = blockIdx.y, tid = threadIdx.x;
    if (tid < 128) al[tid] = alpha[b * TT + tc * 128 + tid];
    __syncthreads();
    int d0 = tid * 4;
    const unsigned short* base = Xb + ((size_t)(b * TT + tc * 128)) * DD + d0;
    f32x4 acc = {0.f, 0.f, 0.f, 0.f};
    #pragma unroll 2
    for (int t = 0; t < 128; t++) {
        ushort4 xv = *(const ushort4*)(base + (size_t)t * DD);
        float a_ = al[t];
        acc[0] += a_ * bf2f(xv.x);
        acc[1] += a_ * bf2f(xv.y);
        acc[2] += a_ * bf2f(xv.z);
        acc[3] += a_ * bf2f(xv.w);
    }
    float* o = r_part + ((size_t)tc * BB + b) * DD + d0;
    *(float4*)o = *(float4*)&acc;
}

// ---------------- K5: out = relu(r @ Wp + lsWx), fused r-reduce + split-K (R5 form) ----
__global__ void final_out(const float* __restrict__ r_part, const float* __restrict__ Wp,
                          const float* __restrict__ lsWx, float* __restrict__ out) {
    __shared__ float rs[DD];
    __shared__ float red[4][64];
    int b = blockIdx.y;
    int e0 = blockIdx.x * 64;
    int tid = threadIdx.x;
    for (int d = tid; d < DD; d += 256) {
        float v = 0.f;
        #pragma unroll
        for (int p = 0; p < 16; p++) v += r_part[((size_t)p * BB + b) * DD + d];
        rs[d] = v;
    }
    __syncthreads();
    int e = tid & 63, dg = tid >> 6;
    int d0 = dg * 256;
    const float* Mp = Wp + (size_t)d0 * DIMQ + e0 + e;
    float acc = 0.f;
    #pragma unroll 8
    for (int d = 0; d < 256; d++) acc += rs[d0 + d] * Mp[(size_t)d * DIMQ];
    red[dg][e] = acc;
    __syncthreads();
    if (dg == 0) {
        float v = red[0][e] + red[1][e] + red[2][e] + red[3][e]
                + lsWx[b * DIMQ + e0 + e];
        out[b * DIMQ + e0 + e] = fmaxf(v, 0.f);
    }
}

extern "C" void kernel_launch(void* const* d_in, const int* in_sizes, int n_in,
                              void* d_out, int out_size, void* d_ws, size_t ws_size,
                              hipStream_t stream) {
    const float* x    = (const float*)d_in[0];  // (B,T,D)
    const float* last = (const float*)d_in[1];  // (B,D)
    const float* Wy   = (const float*)d_in[2];  // (D,DIM)
    const float* Wh   = (const float*)d_in[3];  // (D,DIM)
    const float* w    = (const float*)d_in[4];  // (DIM,1)
    const float* Wp   = (const float*)d_in[5];  // (D,DIM)
    const float* Wx   = (const float*)d_in[6];  // (D,DIM)
    float* out = (float*)d_out;

    // workspace layout (~134 MiB)
    char* ws = (char*)d_ws;
    unsigned short* Xb   = (unsigned short*)(ws);                  // 128 MiB
    unsigned short* WyT  = (unsigned short*)(ws + 134217728);      // 2 MiB
    float* hproj         = (float*)(ws + 136314880);               // 128 KiB
    float* lsWx          = (float*)(ws + 136445952);               // 128 KiB
    float* partials      = (float*)(ws + 136577024);               // 1 MiB (4 x 65536)
    float* alpha         = (float*)(ws + 137625600);               // 256 KiB
    float* r_part        = (float*)(ws + 137887744);               // 2 MiB (16 x 32 x 1024)

    // fused prep: 1024 vecmat2 blocks + 1024 transpose blocks + 65536 cast blocks
    prep_fused<<<67584, 256, 0, stream>>>(x, Xb, Wy, WyT, last, Wh, Wx, hproj, lsWx);
    gemm_scores<<<1024, 512, 0, stream>>>(Xb, WyT, hproj, w, partials);
    softmax_alpha<<<BB, 256, 0, stream>>>(partials, alpha);
    weighted_sum<<<dim3(TT/128, BB), 256, 0, stream>>>(Xb, alpha, r_part);
    final_out<<<dim3(DIMQ/64, BB), 256, 0, stream>>>(r_part, Wp, lsWx, out);
}